// Round 5
// baseline (250.325 us; speedup 1.0000x reference)
//
#include <hip/hip_runtime.h>
#include <math.h>

typedef __attribute__((ext_vector_type(8))) short bf16x8;
typedef __attribute__((ext_vector_type(4))) float f32x4;
typedef __attribute__((ext_vector_type(16))) float f32x16;
typedef __attribute__((ext_vector_type(4))) unsigned u32x4;

__device__ inline short f2bf(float f) {
  unsigned u = __builtin_bit_cast(unsigned, f);
  u = u + 0x7fffu + ((u >> 16) & 1u);
  return (short)(u >> 16);
}
__device__ inline float bf2f(short s) {
  return __builtin_bit_cast(float, ((unsigned)(unsigned short)s) << 16);
}
__device__ inline unsigned cvt_pk_bf16(float lo, float hi) {
  unsigned r;
  asm("v_cvt_pk_bf16_f32 %0, %1, %2" : "=v"(r) : "v"(lo), "v"(hi));
  return r;
}

// async global->LDS, 16B per lane. lds base must be wave-uniform.
__device__ inline void gload16(const short* g, short* l) {
  __builtin_amdgcn_global_load_lds(
      (const __attribute__((address_space(1))) unsigned*)g,
      (__attribute__((address_space(3))) unsigned*)l, 16, 0, 0);
}

// ---------------- all four weight transposes fp32[K,N] -> bf16[N,K] ---------
__global__ __launch_bounds__(256) void wtrans_all(
    const float* __restrict__ wa, const float* __restrict__ wc,
    const float* __restrict__ wf, const float* __restrict__ wm,
    short* __restrict__ oa, short* __restrict__ oc,
    short* __restrict__ of, short* __restrict__ om) {
  __shared__ float tile[32][33];
  int blk = blockIdx.x;
  const float* in; short* out; int K, N, bx;
  if (blk < 1728)      { in = wa; out = oa; K = 768;  N = 2304; bx = 72; }
  else if (blk < 2304) { blk -= 1728; in = wc; out = oc; K = 768;  N = 768;  bx = 24; }
  else if (blk < 4608) { blk -= 2304; in = wf; out = of; K = 768;  N = 3072; bx = 96; }
  else                 { blk -= 4608; in = wm; out = om; K = 3072; N = 768;  bx = 24; }
  const int n0 = (blk % bx) * 32, k0 = (blk / bx) * 32;
  const int tx = threadIdx.x & 31, ty = threadIdx.x >> 5;
  #pragma unroll
  for (int r = ty; r < 32; r += 8)
    tile[r][tx] = in[(size_t)(k0 + r) * N + n0 + tx];
  __syncthreads();
  #pragma unroll
  for (int r = ty; r < 32; r += 8)
    out[(size_t)(n0 + r) * K + k0 + tx] = f2bf(tile[tx][r]);
}

// ---------------- Q' from q (angle-sum folding of rpe) + ktab (bh==0) -------
// Q'[i][cc]    = q_s*sin_i + q_c*cos_i   (pairs with cos_j)
// Q'[i][32+cc] = q_c*sin_i - q_s*cos_i   (pairs with sin_j)
__global__ __launch_bounds__(256) void qprime_kernel(
    const short* __restrict__ qkv, short* __restrict__ qpr,
    short* __restrict__ ktab) {
  const int idx = blockIdx.x * 256 + threadIdx.x;  // 48*1024*32
  const int cc = idx & 31;
  const int row = idx >> 5;            // bh*1024 + i
  const int i = row & 1023, bh = row >> 10;
  const int b = bh / 12, h = bh % 12;
  const float invf = exp2f(-(float)cc * (13.287712379549449f / 32.0f));
  const float ang = (float)i * invf;
  float si, co;
  __sincosf(ang, &si, &co);
  if (bh == 0) {
    ktab[i * 64 + cc]      = f2bf(co);
    ktab[i * 64 + 32 + cc] = f2bf(si);
  }
  const short* q = qkv + (size_t)(b * 1024 + i) * 2304 + h * 64;
  const float qs = bf2f(q[cc]), qc = bf2f(q[32 + cc]);
  qpr[(size_t)row * 64 + cc]      = f2bf(qs * si + qc * co);
  qpr[(size_t)row * 64 + 32 + cc] = f2bf(qc * si - qs * co);
}

// ---------------- LayerNorm fp32 row(768) -> bf16 ----------------
__global__ __launch_bounds__(256) void ln_kernel(
    const float* __restrict__ x, const float* __restrict__ w,
    short* __restrict__ out) {
  const int row = blockIdx.x, tid = threadIdx.x;
  const float* xr = x + (size_t)row * 768;
  float v0 = xr[tid], v1 = xr[tid + 256], v2 = xr[tid + 512];
  float s = v0 + v1 + v2;
  #pragma unroll
  for (int o = 1; o < 64; o <<= 1) s += __shfl_xor(s, o);
  __shared__ float red[8];
  const int wv = tid >> 6;
  if ((tid & 63) == 0) red[wv] = s;
  __syncthreads();
  const float mean = (red[0] + red[1] + red[2] + red[3]) * (1.0f / 768.0f);
  v0 -= mean; v1 -= mean; v2 -= mean;
  float q = v0 * v0 + v1 * v1 + v2 * v2;
  #pragma unroll
  for (int o = 1; o < 64; o <<= 1) q += __shfl_xor(q, o);
  if ((tid & 63) == 0) red[4 + wv] = q;
  __syncthreads();
  const float var = (red[4] + red[5] + red[6] + red[7]) * (1.0f / 768.0f);
  const float inv = 1.0f / sqrtf(var + 1e-5f);
  out[(size_t)row * 768 + tid]       = f2bf(v0 * inv * w[tid]);
  out[(size_t)row * 768 + tid + 256] = f2bf(v1 * inv * w[tid + 256]);
  out[(size_t)row * 768 + tid + 512] = f2bf(v2 * inv * w[tid + 512]);
}

// ---------------- V transpose: qkv v-part -> vT[b,h,d,t] ----------------
__global__ __launch_bounds__(256) void vtrans_kernel(
    const short* __restrict__ qkv, short* __restrict__ vT) {
  __shared__ short tile[64][65];
  const int blk = blockIdx.x;
  const int bh = blk >> 4, t0 = (blk & 15) * 64;
  const int b = bh / 12, h = bh % 12;
  const int tx = threadIdx.x & 63, ty = threadIdx.x >> 6;
  const short* src = qkv + (size_t)(b * 1024 + t0) * 2304 + 1536 + h * 64;
  #pragma unroll
  for (int r = ty; r < 64; r += 4)
    tile[r][tx] = src[(size_t)r * 2304 + tx];
  __syncthreads();
  short* dst = vT + (size_t)bh * 64 * 1024 + t0;
  #pragma unroll
  for (int r = ty; r < 64; r += 4)
    dst[(size_t)r * 1024 + tx] = tile[tx][r];
}

// ---------------- GEMM: C[M,N] = A[M,K](bf16) x Bt[N,K](bf16) ----------------
// 2-phase double-buffered global_load_lds staging; ONE barrier per K-step.
// EPI 0: bf16 store  1: f32 out=res+acc  2: bf16 gelu  3: f32 split-K partial
template <int EPI, int BM, int BN>
__global__ __launch_bounds__(256) void gemm_bt(
    const short* __restrict__ A, const short* __restrict__ Bt,
    const float* __restrict__ res, float* __restrict__ outF,
    short* __restrict__ outB, int M, int N, int K, int lda, int ldb) {
  __shared__ __align__(16) short As[2][BM * 32];
  __shared__ __align__(16) short Bs[2][BN * 32];
  constexpr int WM = BM / 2, WN = BN / 2;
  constexpr int MI = WM / 16, NJ = WN / 16;
  const int tid = threadIdx.x;
  const int w = tid >> 6, lane = tid & 63;
  const int m0 = blockIdx.y * BM, n0 = blockIdx.x * BN;
  const int wm = (w >> 1) * WM, wn = (w & 1) * WN;
  const int lr = lane >> 2;
  const int lc = (lane & 3) * 8;
  if constexpr (EPI == 3) {
    A += (size_t)blockIdx.z * K;
    Bt += (size_t)blockIdx.z * K;
    outF += (size_t)blockIdx.z * M * N;
  }
  f32x4 acc[MI][NJ];
  #pragma unroll
  for (int i = 0; i < MI; i++)
    #pragma unroll
    for (int j = 0; j < NJ; j++)
      #pragma unroll
      for (int r = 0; r < 4; r++) acc[i][j][r] = 0.0f;

  const int nt = K / 32;
  // prologue stage into buf 0
  #pragma unroll
  for (int p = 0; p < BM / 64; ++p)
    gload16(A + (size_t)(m0 + p * 64 + w * 16 + lr) * lda + lc,
            &As[0][p * 2048 + w * 512]);
  #pragma unroll
  for (int p = 0; p < BN / 64; ++p)
    gload16(Bt + (size_t)(n0 + p * 64 + w * 16 + lr) * ldb + lc,
            &Bs[0][p * 2048 + w * 512]);
  __syncthreads();

  for (int t = 0; t < nt; ++t) {
    const int cur = t & 1;
    if (t + 1 < nt) {
      const int kt = (t + 1) * 32;
      #pragma unroll
      for (int p = 0; p < BM / 64; ++p)
        gload16(A + (size_t)(m0 + p * 64 + w * 16 + lr) * lda + kt + lc,
                &As[cur ^ 1][p * 2048 + w * 512]);
      #pragma unroll
      for (int p = 0; p < BN / 64; ++p)
        gload16(Bt + (size_t)(n0 + p * 64 + w * 16 + lr) * ldb + kt + lc,
                &Bs[cur ^ 1][p * 2048 + w * 512]);
    }
    bf16x8 af[MI], bfr[NJ];
    #pragma unroll
    for (int i = 0; i < MI; i++)
      af[i] = *(const bf16x8*)&As[cur][(wm + i * 16 + (lane & 15)) * 32 + (lane >> 4) * 8];
    #pragma unroll
    for (int j = 0; j < NJ; j++)
      bfr[j] = *(const bf16x8*)&Bs[cur][(wn + j * 16 + (lane & 15)) * 32 + (lane >> 4) * 8];
    #pragma unroll
    for (int i = 0; i < MI; i++)
      #pragma unroll
      for (int j = 0; j < NJ; j++)
        acc[i][j] = __builtin_amdgcn_mfma_f32_16x16x32_bf16(af[i], bfr[j],
                                                            acc[i][j], 0, 0, 0);
    __syncthreads();
  }
  const int r0 = (lane >> 4) * 4, cl = lane & 15;
  #pragma unroll
  for (int i = 0; i < MI; i++) {
    #pragma unroll
    for (int j = 0; j < NJ; j++) {
      const int gm = m0 + wm + i * 16 + r0;
      const int gn = n0 + wn + j * 16 + cl;
      #pragma unroll
      for (int r = 0; r < 4; r++) {
        const size_t idx = (size_t)(gm + r) * N + gn;
        const float v = acc[i][j][r];
        if constexpr (EPI == 0) {
          outB[idx] = f2bf(v);
        } else if constexpr (EPI == 1) {
          outF[idx] = res[idx] + v;
        } else if constexpr (EPI == 2) {
          outB[idx] = f2bf(0.5f * v * (1.0f + erff(v * 0.70710678118f)));
        } else {
          outF[idx] = v;
        }
      }
    }
  }
}

// ---------------- split-K reduce: out = res + sum_z Cp[z] ----------------
__global__ __launch_bounds__(256) void reduce_splitk(
    const float* __restrict__ Cp, const float* __restrict__ res,
    float* __restrict__ out) {
  const size_t i4 = ((size_t)blockIdx.x * 256 + threadIdx.x) * 4;
  float4 a = *(const float4*)(res + i4);
  #pragma unroll
  for (int z = 0; z < 4; ++z) {
    float4 p = *(const float4*)(Cp + (size_t)z * 3145728 + i4);
    a.x += p.x; a.y += p.y; a.z += p.z; a.w += p.w;
  }
  *(float4*)(out + i4) = a;
}

// ---------------- fused attention: 8 waves/block, in-LDS combine -------------
// block = (bh, it); wave w handles chunk jt in [4w, min(4w+3,it)], idle if 4w>it.
// Head-dim-128 QK' (rpe folded); exp2-domain online softmax; permlane P redist.
__global__ __launch_bounds__(512) void attn_fused(
    const short* __restrict__ qkv, const short* __restrict__ vT,
    const short* __restrict__ qpr, const short* __restrict__ ktab,
    short* __restrict__ yout) {
  __shared__ float Ylds[8][32][64];          // 64 KB
  __shared__ float Mlds[8][32], Llds[8][32]; // 2 KB
  const int blk = blockIdx.x;  // bh*32 + it
  const int it = blk & 31, bh = blk >> 5;
  const int b = bh / 12, h = bh % 12;
  const int I0 = it * 32;
  const int tid = threadIdx.x;
  const int w = tid >> 6;       // chunk id
  const int lane = tid & 63;
  const int li = lane & 31, hi = lane >> 5;
  const int g = it >> 2;
  const bool active = (w <= g);
  constexpr float SCALE2 = 0.125f * 1.44269504089f;  // 1/sqrt(64) * log2(e)

  if (active) {
    // Qaug fragments: [q(64) | Q'(64)]
    const short* qrow = qkv + (size_t)(b * 1024 + I0 + li) * 2304 + h * 64;
    const short* qprow = qpr + ((size_t)bh * 1024 + I0 + li) * 64;
    bf16x8 qf[8];
    #pragma unroll
    for (int s = 0; s < 4; s++) {
      qf[s]     = *(const bf16x8*)(qrow + s * 16 + hi * 8);
      qf[4 + s] = *(const bf16x8*)(qprow + s * 16 + hi * 8);
    }
    const short* kbase = qkv + (size_t)(b * 1024) * 2304 + 768 + h * 64;
    const short* vbase = vT + (size_t)bh * 64 * 1024;

    float m_run = -1e30f, l_run = 0.0f;
    f32x16 ya0, ya1;
    #pragma unroll
    for (int r = 0; r < 16; r++) { ya0[r] = 0.0f; ya1[r] = 0.0f; }

    const int jt0 = w * 4;
    const int jt1 = (w * 4 + 3 < it) ? (w * 4 + 3) : it;

    // prefetch Kaug for first tile
    bf16x8 kn[8];
    {
      const short* kb = kbase + (size_t)(jt0 * 32 + li) * 2304;
      const short* kt = ktab + (size_t)(jt0 * 32 + li) * 64;
      #pragma unroll
      for (int s = 0; s < 4; s++) {
        kn[s]     = *(const bf16x8*)(kb + s * 16 + hi * 8);
        kn[4 + s] = *(const bf16x8*)(kt + s * 16 + hi * 8);
      }
    }

    for (int jt = jt0; jt <= jt1; ++jt) {
      const int J0 = jt * 32;
      bf16x8 kf[8];
      #pragma unroll
      for (int s = 0; s < 8; s++) kf[s] = kn[s];
      if (jt < jt1) {
        const short* kb = kbase + (size_t)((jt + 1) * 32 + li) * 2304;
        const short* kt = ktab + (size_t)((jt + 1) * 32 + li) * 64;
        #pragma unroll
        for (int s = 0; s < 4; s++) {
          kn[s]     = *(const bf16x8*)(kb + s * 16 + hi * 8);
          kn[4 + s] = *(const bf16x8*)(kt + s * 16 + hi * 8);
        }
      }
      // V loads issued early
      bf16x8 vc[4];
      #pragma unroll
      for (int s = 0; s < 2; s++) {
        vc[s * 2]     = *(const bf16x8*)(vbase + (size_t)li * 1024 + J0 + s * 16 + hi * 8);
        vc[s * 2 + 1] = *(const bf16x8*)(vbase + (size_t)(32 + li) * 1024 + J0 + s * 16 + hi * 8);
      }
      // --- S^T = Kaug . Qaug^T, two independent chains ---
      f32x16 sa0, sa1;
      #pragma unroll
      for (int r = 0; r < 16; r++) { sa0[r] = 0.0f; sa1[r] = 0.0f; }
      #pragma unroll
      for (int s = 0; s < 4; s++) {
        sa0 = __builtin_amdgcn_mfma_f32_32x32x16_bf16(kf[2 * s],     qf[2 * s],     sa0, 0, 0, 0);
        sa1 = __builtin_amdgcn_mfma_f32_32x32x16_bf16(kf[2 * s + 1], qf[2 * s + 1], sa1, 0, 0, 0);
      }
      // --- scale (log2 domain), mask only on diagonal tile, online softmax ---
      float sv[16];
      float mx = -1e30f;
      if (jt == it) {
        #pragma unroll
        for (int r = 0; r < 16; r++) {
          const int j = (r & 3) + 8 * (r >> 2) + 4 * hi;
          float v = (sa0[r] + sa1[r]) * SCALE2;
          v = (j <= li) ? v : -1e30f;
          sv[r] = v;
          mx = fmaxf(mx, v);
        }
      } else {
        #pragma unroll
        for (int r = 0; r < 16; r++) {
          const float v = (sa0[r] + sa1[r]) * SCALE2;
          sv[r] = v;
          mx = fmaxf(mx, v);
        }
      }
      mx = fmaxf(mx, __shfl_xor(mx, 32));
      float mref = m_run;
      float alpha = 1.0f;
      const bool resc = !__all(mx <= m_run + 11.5f);  // defer-max (T13)
      if (resc) {
        mref = fmaxf(m_run, mx);
        alpha = exp2f(m_run - mref);
        m_run = mref;
      }
      float psum = 0.0f;
      unsigned pw[8];
      #pragma unroll
      for (int t = 0; t < 8; t++) {
        const float p0 = exp2f(sv[2 * t] - mref);
        const float p1 = exp2f(sv[2 * t + 1] - mref);
        psum += p0 + p1;
        pw[t] = cvt_pk_bf16(p0, p1);
      }
      psum += __shfl_xor(psum, 32);
      l_run = l_run * alpha + psum;
      if (resc) {
        #pragma unroll
        for (int r = 0; r < 16; r++) {
          const int row = (r & 3) + 8 * (r >> 2) + 4 * hi;
          const float a = __shfl(alpha, row);
          ya0[r] *= a;
          ya1[r] *= a;
        }
      }
      // --- PV: redistribute P via permlane32_swap, then MFMA ---
      #pragma unroll
      for (int s = 0; s < 2; s++) {
        unsigned a0 = pw[4 * s],     b0 = pw[4 * s + 2];
        unsigned a1 = pw[4 * s + 1], b1 = pw[4 * s + 3];
        asm volatile("v_permlane32_swap_b32 %0, %1" : "+v"(a0), "+v"(b0));
        asm volatile("v_permlane32_swap_b32 %0, %1" : "+v"(a1), "+v"(b1));
        u32x4 t4;
        t4[0] = a0; t4[1] = a1; t4[2] = b0; t4[3] = b1;
        const bf16x8 pf = __builtin_bit_cast(bf16x8, t4);
        ya0 = __builtin_amdgcn_mfma_f32_32x32x16_bf16(pf, vc[s * 2],     ya0, 0, 0, 0);
        ya1 = __builtin_amdgcn_mfma_f32_32x32x16_bf16(pf, vc[s * 2 + 1], ya1, 0, 0, 0);
      }
    }
    // --- write partials to LDS ---
    if (hi == 0) {
      Mlds[w][li] = m_run;
      Llds[w][li] = l_run;
    }
    #pragma unroll
    for (int r = 0; r < 16; r++) {
      const int row = (r & 3) + 8 * (r >> 2) + 4 * hi;
      Ylds[w][row][li]      = ya0[r];
      Ylds[w][row][32 + li] = ya1[r];
    }
  }
  __syncthreads();
  // --- in-block combine: thread owns (row, 4 cols) ---
  const int row = tid >> 4;
  const int c4 = (tid & 15) * 4;
  float m = -1e30f;
  for (int cI = 0; cI <= g; ++cI) m = fmaxf(m, Mlds[cI][row]);
  float L = 0.0f, y0 = 0.0f, y1 = 0.0f, y2 = 0.0f, y3 = 0.0f;
  for (int cI = 0; cI <= g; ++cI) {
    const float wgt = exp2f(Mlds[cI][row] - m);
    L += Llds[cI][row] * wgt;
    const float* yr = &Ylds[cI][row][c4];
    y0 += yr[0] * wgt; y1 += yr[1] * wgt; y2 += yr[2] * wgt; y3 += yr[3] * wgt;
  }
  const float inv = 1.0f / L;
  uint2 o;
  o.x = cvt_pk_bf16(y0 * inv, y1 * inv);
  o.y = cvt_pk_bf16(y2 * inv, y3 * inv);
  *(uint2*)(yout + (size_t)(b * 1024 + I0 + row) * 768 + h * 64 + c4) = o;
}

// ---------------- launch ----------------
extern "C" void kernel_launch(void* const* d_in, const int* in_sizes, int n_in,
                              void* d_out, int out_size, void* d_ws, size_t ws_size,
                              hipStream_t stream) {
  const float* x       = (const float*)d_in[0];
  const float* ln1_w   = (const float*)d_in[1];
  const float* w_attn  = (const float*)d_in[2];
  // d_in[3] = w_pos (dead code in reference)
  const float* w_cproj = (const float*)d_in[4];
  const float* ln2_w   = (const float*)d_in[5];
  const float* w_fc    = (const float*)d_in[6];
  const float* w_mproj = (const float*)d_in[7];
  float* out = (float*)d_out;
  char* ws = (char*)d_ws;

  short* wT_attn  = (short*)(ws + 0);          // [2304][768]
  short* wT_cproj = (short*)(ws + 3538944);    // [768][768]
  short* wT_fc    = (short*)(ws + 4718592);    // [3072][768]
  short* wT_mproj = (short*)(ws + 9437184);    // [768][3072]
  short* ktab     = (short*)(ws + 14155776);   // [1024][64] bf16 (128KB)
  short* h_bf     = (short*)(ws + 14417920);   // [4096][768]; reused as qpr
  short* qpr      = (short*)(ws + 14417920);   // [48*1024][64] (h_bf dead then)
  short* qkv_bf   = (short*)(ws + 20709376);   // [4096][2304]
  short* vT       = (short*)(ws + 39583744);   // [48][64][1024]
  short* y_att    = (short*)(ws + 45875200);   // [4096][768]
  short* h2_bf    = (short*)(ws + 52166656);   // [4096][768]
  short* hfc_bf   = (short*)(ws + 58458112);   // [4096][3072]
  // split-K partials (after hfc_bf): 4 x [4096][768] f32 = 48MB
  float* Cpart = (float*)(ws + 83623936);
  const bool use_splitk = ws_size >= 133955584ull;

  // weight prep
  wtrans_all<<<6912, 256, 0, stream>>>(w_attn, w_cproj, w_fc, w_mproj,
                                       wT_attn, wT_cproj, wT_fc, wT_mproj);

  // attention branch
  ln_kernel<<<4096, 256, 0, stream>>>(x, ln1_w, h_bf);
  gemm_bt<0, 128, 128><<<dim3(18, 32), 256, 0, stream>>>(
      h_bf, wT_attn, nullptr, nullptr, qkv_bf, 4096, 2304, 768, 768, 768);
  qprime_kernel<<<6144, 256, 0, stream>>>(qkv_bf, qpr, ktab);
  vtrans_kernel<<<768, 256, 0, stream>>>(qkv_bf, vT);
  attn_fused<<<1536, 512, 0, stream>>>(qkv_bf, vT, qpr, ktab, y_att);
  gemm_bt<1, 64, 64><<<dim3(12, 64), 256, 0, stream>>>(
      y_att, wT_cproj, x, out, nullptr, 4096, 768, 768, 768, 768);
  // MLP branch
  ln_kernel<<<4096, 256, 0, stream>>>(out, ln2_w, h2_bf);
  gemm_bt<2, 128, 128><<<dim3(24, 32), 256, 0, stream>>>(
      h2_bf, wT_fc, nullptr, nullptr, hfc_bf, 4096, 3072, 768, 768, 768);
  if (use_splitk) {
    gemm_bt<3, 128, 128><<<dim3(6, 32, 4), 256, 0, stream>>>(
        hfc_bf, wT_mproj, nullptr, Cpart, nullptr, 4096, 768, 768, 3072, 3072);
    reduce_splitk<<<3072, 256, 0, stream>>>(Cpart, out, out);
  } else {
    gemm_bt<1, 64, 64><<<dim3(12, 64), 256, 0, stream>>>(
        hfc_bf, wT_mproj, out, out, nullptr, 4096, 768, 3072, 3072, 3072);
  }
}

// Round 6
// 228.150 us; speedup vs baseline: 1.0972x; 1.0972x over previous
//
#include <hip/hip_runtime.h>
#include <math.h>

typedef __attribute__((ext_vector_type(8))) short bf16x8;
typedef __attribute__((ext_vector_type(4))) float f32x4;
typedef __attribute__((ext_vector_type(16))) float f32x16;
typedef __attribute__((ext_vector_type(4))) unsigned u32x4;

__device__ inline short f2bf(float f) {
  unsigned u = __builtin_bit_cast(unsigned, f);
  u = u + 0x7fffu + ((u >> 16) & 1u);
  return (short)(u >> 16);
}
__device__ inline float bf2f(short s) {
  return __builtin_bit_cast(float, ((unsigned)(unsigned short)s) << 16);
}
__device__ inline unsigned cvt_pk_bf16(float lo, float hi) {
  unsigned r;
  asm("v_cvt_pk_bf16_f32 %0, %1, %2" : "=v"(r) : "v"(lo), "v"(hi));
  return r;
}

// async global->LDS, 16B per lane. lds base must be wave-uniform.
__device__ inline void gload16(const short* g, short* l) {
  __builtin_amdgcn_global_load_lds(
      (const __attribute__((address_space(1))) unsigned*)g,
      (__attribute__((address_space(3))) unsigned*)l, 16, 0, 0);
}

// ---------------- all four weight transposes fp32[K,N] -> bf16[N,K] ---------
__global__ __launch_bounds__(256) void wtrans_all(
    const float* __restrict__ wa, const float* __restrict__ wc,
    const float* __restrict__ wf, const float* __restrict__ wm,
    short* __restrict__ oa, short* __restrict__ oc,
    short* __restrict__ of, short* __restrict__ om) {
  __shared__ float tile[32][33];
  int blk = blockIdx.x;
  const float* in; short* out; int K, N, bx;
  if (blk < 1728)      { in = wa; out = oa; K = 768;  N = 2304; bx = 72; }
  else if (blk < 2304) { blk -= 1728; in = wc; out = oc; K = 768;  N = 768;  bx = 24; }
  else if (blk < 4608) { blk -= 2304; in = wf; out = of; K = 768;  N = 3072; bx = 96; }
  else                 { blk -= 4608; in = wm; out = om; K = 3072; N = 768;  bx = 24; }
  const int n0 = (blk % bx) * 32, k0 = (blk / bx) * 32;
  const int tx = threadIdx.x & 31, ty = threadIdx.x >> 5;
  #pragma unroll
  for (int r = ty; r < 32; r += 8)
    tile[r][tx] = in[(size_t)(k0 + r) * N + n0 + tx];
  __syncthreads();
  #pragma unroll
  for (int r = ty; r < 32; r += 8)
    out[(size_t)(n0 + r) * K + k0 + tx] = f2bf(tile[tx][r]);
}

// ---------------- Q' from q (angle-sum folding of rpe) + ktab (bh==0) -------
__global__ __launch_bounds__(256) void qprime_kernel(
    const short* __restrict__ qkv, short* __restrict__ qpr,
    short* __restrict__ ktab) {
  const int idx = blockIdx.x * 256 + threadIdx.x;  // 48*1024*32
  const int cc = idx & 31;
  const int row = idx >> 5;            // bh*1024 + i
  const int i = row & 1023, bh = row >> 10;
  const int b = bh / 12, h = bh % 12;
  const float invf = exp2f(-(float)cc * (13.287712379549449f / 32.0f));
  const float ang = (float)i * invf;
  float si, co;
  __sincosf(ang, &si, &co);
  if (bh == 0) {
    ktab[i * 64 + cc]      = f2bf(co);
    ktab[i * 64 + 32 + cc] = f2bf(si);
  }
  const short* q = qkv + (size_t)(b * 1024 + i) * 2304 + h * 64;
  const float qs = bf2f(q[cc]), qc = bf2f(q[32 + cc]);
  qpr[(size_t)row * 64 + cc]      = f2bf(qs * si + qc * co);
  qpr[(size_t)row * 64 + 32 + cc] = f2bf(qc * si - qs * co);
}

// ---------------- LayerNorm fp32 row(768) -> bf16 ----------------
__global__ __launch_bounds__(256) void ln_kernel(
    const float* __restrict__ x, const float* __restrict__ w,
    short* __restrict__ out) {
  const int row = blockIdx.x, tid = threadIdx.x;
  const float* xr = x + (size_t)row * 768;
  float v0 = xr[tid], v1 = xr[tid + 256], v2 = xr[tid + 512];
  float s = v0 + v1 + v2;
  #pragma unroll
  for (int o = 1; o < 64; o <<= 1) s += __shfl_xor(s, o);
  __shared__ float red[8];
  const int wv = tid >> 6;
  if ((tid & 63) == 0) red[wv] = s;
  __syncthreads();
  const float mean = (red[0] + red[1] + red[2] + red[3]) * (1.0f / 768.0f);
  v0 -= mean; v1 -= mean; v2 -= mean;
  float q = v0 * v0 + v1 * v1 + v2 * v2;
  #pragma unroll
  for (int o = 1; o < 64; o <<= 1) q += __shfl_xor(q, o);
  if ((tid & 63) == 0) red[4 + wv] = q;
  __syncthreads();
  const float var = (red[4] + red[5] + red[6] + red[7]) * (1.0f / 768.0f);
  const float inv = 1.0f / sqrtf(var + 1e-5f);
  out[(size_t)row * 768 + tid]       = f2bf(v0 * inv * w[tid]);
  out[(size_t)row * 768 + tid + 256] = f2bf(v1 * inv * w[tid + 256]);
  out[(size_t)row * 768 + tid + 512] = f2bf(v2 * inv * w[tid + 512]);
}

// ---------------- V transpose: qkv v-part -> vT[b,h,d,t] ----------------
__global__ __launch_bounds__(256) void vtrans_kernel(
    const short* __restrict__ qkv, short* __restrict__ vT) {
  __shared__ short tile[64][65];
  const int blk = blockIdx.x;
  const int bh = blk >> 4, t0 = (blk & 15) * 64;
  const int b = bh / 12, h = bh % 12;
  const int tx = threadIdx.x & 63, ty = threadIdx.x >> 6;
  const short* src = qkv + (size_t)(b * 1024 + t0) * 2304 + 1536 + h * 64;
  #pragma unroll
  for (int r = ty; r < 64; r += 4)
    tile[r][tx] = src[(size_t)r * 2304 + tx];
  __syncthreads();
  short* dst = vT + (size_t)bh * 64 * 1024 + t0;
  #pragma unroll
  for (int r = ty; r < 64; r += 4)
    dst[(size_t)r * 1024 + tx] = tile[tx][r];
}

// ---------------- GEMM: C[M,N] = A[M,K](bf16) x Bt[N,K](bf16) ----------------
// 2-phase double-buffered global_load_lds staging; ONE barrier per K-step.
// EPI 0: bf16 store  1: f32 out=res+acc  2: bf16 gelu  3: f32 split-K partial
template <int EPI, int BM, int BN>
__global__ __launch_bounds__(256) void gemm_bt(
    const short* __restrict__ A, const short* __restrict__ Bt,
    const float* __restrict__ res, float* __restrict__ outF,
    short* __restrict__ outB, int M, int N, int K, int lda, int ldb) {
  __shared__ __align__(16) short As[2][BM * 32];
  __shared__ __align__(16) short Bs[2][BN * 32];
  constexpr int WM = BM / 2, WN = BN / 2;
  constexpr int MI = WM / 16, NJ = WN / 16;
  const int tid = threadIdx.x;
  const int w = tid >> 6, lane = tid & 63;
  const int m0 = blockIdx.y * BM, n0 = blockIdx.x * BN;
  const int wm = (w >> 1) * WM, wn = (w & 1) * WN;
  const int lr = lane >> 2;
  const int lc = (lane & 3) * 8;
  if constexpr (EPI == 3) {
    A += (size_t)blockIdx.z * K;
    Bt += (size_t)blockIdx.z * K;
    outF += (size_t)blockIdx.z * M * N;
  }
  f32x4 acc[MI][NJ];
  #pragma unroll
  for (int i = 0; i < MI; i++)
    #pragma unroll
    for (int j = 0; j < NJ; j++)
      #pragma unroll
      for (int r = 0; r < 4; r++) acc[i][j][r] = 0.0f;

  const int nt = K / 32;
  // prologue stage into buf 0
  #pragma unroll
  for (int p = 0; p < BM / 64; ++p)
    gload16(A + (size_t)(m0 + p * 64 + w * 16 + lr) * lda + lc,
            &As[0][p * 2048 + w * 512]);
  #pragma unroll
  for (int p = 0; p < BN / 64; ++p)
    gload16(Bt + (size_t)(n0 + p * 64 + w * 16 + lr) * ldb + lc,
            &Bs[0][p * 2048 + w * 512]);
  __syncthreads();

  for (int t = 0; t < nt; ++t) {
    const int cur = t & 1;
    if (t + 1 < nt) {
      const int kt = (t + 1) * 32;
      #pragma unroll
      for (int p = 0; p < BM / 64; ++p)
        gload16(A + (size_t)(m0 + p * 64 + w * 16 + lr) * lda + kt + lc,
                &As[cur ^ 1][p * 2048 + w * 512]);
      #pragma unroll
      for (int p = 0; p < BN / 64; ++p)
        gload16(Bt + (size_t)(n0 + p * 64 + w * 16 + lr) * ldb + kt + lc,
                &Bs[cur ^ 1][p * 2048 + w * 512]);
    }
    bf16x8 af[MI], bfr[NJ];
    #pragma unroll
    for (int i = 0; i < MI; i++)
      af[i] = *(const bf16x8*)&As[cur][(wm + i * 16 + (lane & 15)) * 32 + (lane >> 4) * 8];
    #pragma unroll
    for (int j = 0; j < NJ; j++)
      bfr[j] = *(const bf16x8*)&Bs[cur][(wn + j * 16 + (lane & 15)) * 32 + (lane >> 4) * 8];
    #pragma unroll
    for (int i = 0; i < MI; i++)
      #pragma unroll
      for (int j = 0; j < NJ; j++)
        acc[i][j] = __builtin_amdgcn_mfma_f32_16x16x32_bf16(af[i], bfr[j],
                                                            acc[i][j], 0, 0, 0);
    __syncthreads();
  }
  const int r0 = (lane >> 4) * 4, cl = lane & 15;
  #pragma unroll
  for (int i = 0; i < MI; i++) {
    #pragma unroll
    for (int j = 0; j < NJ; j++) {
      const int gm = m0 + wm + i * 16 + r0;
      const int gn = n0 + wn + j * 16 + cl;
      #pragma unroll
      for (int r = 0; r < 4; r++) {
        const size_t idx = (size_t)(gm + r) * N + gn;
        const float v = acc[i][j][r];
        if constexpr (EPI == 0) {
          outB[idx] = f2bf(v);
        } else if constexpr (EPI == 1) {
          outF[idx] = res[idx] + v;
        } else if constexpr (EPI == 2) {
          outB[idx] = f2bf(0.5f * v * (1.0f + erff(v * 0.70710678118f)));
        } else {
          outF[idx] = v;
        }
      }
    }
  }
}

// ---------------- split-K=2 reduce: out = res + sum_z Cp[z] ----------------
__global__ __launch_bounds__(256) void reduce_splitk(
    const float* __restrict__ Cp, const float* __restrict__ res,
    float* __restrict__ out) {
  const size_t i4 = ((size_t)blockIdx.x * 256 + threadIdx.x) * 4;
  float4 a = *(const float4*)(res + i4);
  #pragma unroll
  for (int z = 0; z < 2; ++z) {
    float4 p = *(const float4*)(Cp + (size_t)z * 3145728 + i4);
    a.x += p.x; a.y += p.y; a.z += p.z; a.w += p.w;
  }
  *(float4*)(out + i4) = a;
}

// ---------------- attention partials: 8 INDEPENDENT waves per block ---------
// Task enumeration is c-major per bh: task = bh*144 + off(c) + (it-4c),
// off(c) = 34c - 2c^2. The 8 waves of a block take 8 consecutive tasks ->
// same bh, same K/V j-window (L1/L2 reuse). No LDS, no barrier.
__global__ __launch_bounds__(512) void attn_part8(
    const short* __restrict__ qkv, const short* __restrict__ vT,
    const short* __restrict__ qpr, const short* __restrict__ ktab,
    float* __restrict__ mpart, float* __restrict__ lpart,
    short* __restrict__ Ypart) {
  const int tid = threadIdx.x;
  const int task = blockIdx.x * 8 + (tid >> 6);
  const int bh = task / 144;
  const int rem = task % 144;
  int c = 0;
  #pragma unroll
  for (int cc = 0; cc < 7; ++cc)
    if (rem >= 34 * (cc + 1) - 2 * (cc + 1) * (cc + 1)) c = cc + 1;
  const int it = 4 * c + (rem - (34 * c - 2 * c * c));
  const int b = bh / 12, h = bh % 12;
  const int I0 = it * 32;
  const int lane = tid & 63;
  const int li = lane & 31, hi = lane >> 5;
  constexpr float SCALE2 = 0.125f * 1.44269504089f;  // 1/sqrt(64) * log2(e)

  // Qaug fragments: [q(64) | Q'(64)]
  const short* qrow = qkv + (size_t)(b * 1024 + I0 + li) * 2304 + h * 64;
  const short* qprow = qpr + ((size_t)bh * 1024 + I0 + li) * 64;
  bf16x8 qf[8];
  #pragma unroll
  for (int s = 0; s < 4; s++) {
    qf[s]     = *(const bf16x8*)(qrow + s * 16 + hi * 8);
    qf[4 + s] = *(const bf16x8*)(qprow + s * 16 + hi * 8);
  }
  const short* kbase = qkv + (size_t)(b * 1024) * 2304 + 768 + h * 64;
  const short* vbase = vT + (size_t)bh * 64 * 1024;

  float m_run = -1e30f, l_run = 0.0f;
  f32x16 ya0, ya1;
  #pragma unroll
  for (int r = 0; r < 16; r++) { ya0[r] = 0.0f; ya1[r] = 0.0f; }

  const int jt0 = c * 4;
  const int jt1 = (c * 4 + 3 < it) ? (c * 4 + 3) : it;

  // prefetch Kaug for first tile
  bf16x8 kn[8];
  {
    const short* kb = kbase + (size_t)(jt0 * 32 + li) * 2304;
    const short* kt = ktab + (size_t)(jt0 * 32 + li) * 64;
    #pragma unroll
    for (int s = 0; s < 4; s++) {
      kn[s]     = *(const bf16x8*)(kb + s * 16 + hi * 8);
      kn[4 + s] = *(const bf16x8*)(kt + s * 16 + hi * 8);
    }
  }

  for (int jt = jt0; jt <= jt1; ++jt) {
    const int J0 = jt * 32;
    bf16x8 kf[8];
    #pragma unroll
    for (int s = 0; s < 8; s++) kf[s] = kn[s];
    if (jt < jt1) {
      const short* kb = kbase + (size_t)((jt + 1) * 32 + li) * 2304;
      const short* kt = ktab + (size_t)((jt + 1) * 32 + li) * 64;
      #pragma unroll
      for (int s = 0; s < 4; s++) {
        kn[s]     = *(const bf16x8*)(kb + s * 16 + hi * 8);
        kn[4 + s] = *(const bf16x8*)(kt + s * 16 + hi * 8);
      }
    }
    // V loads issued early
    bf16x8 vc[4];
    #pragma unroll
    for (int s = 0; s < 2; s++) {
      vc[s * 2]     = *(const bf16x8*)(vbase + (size_t)li * 1024 + J0 + s * 16 + hi * 8);
      vc[s * 2 + 1] = *(const bf16x8*)(vbase + (size_t)(32 + li) * 1024 + J0 + s * 16 + hi * 8);
    }
    // --- S^T = Kaug . Qaug^T, two independent chains ---
    f32x16 sa0, sa1;
    #pragma unroll
    for (int r = 0; r < 16; r++) { sa0[r] = 0.0f; sa1[r] = 0.0f; }
    __builtin_amdgcn_s_setprio(1);
    #pragma unroll
    for (int s = 0; s < 4; s++) {
      sa0 = __builtin_amdgcn_mfma_f32_32x32x16_bf16(kf[2 * s],     qf[2 * s],     sa0, 0, 0, 0);
      sa1 = __builtin_amdgcn_mfma_f32_32x32x16_bf16(kf[2 * s + 1], qf[2 * s + 1], sa1, 0, 0, 0);
    }
    __builtin_amdgcn_s_setprio(0);
    // --- scale (log2 domain), mask only on diagonal tile, online softmax ---
    float sv[16];
    float mx = -1e30f;
    if (jt == it) {
      #pragma unroll
      for (int r = 0; r < 16; r++) {
        const int j = (r & 3) + 8 * (r >> 2) + 4 * hi;
        float v = (sa0[r] + sa1[r]) * SCALE2;
        v = (j <= li) ? v : -1e30f;
        sv[r] = v;
        mx = fmaxf(mx, v);
      }
    } else {
      #pragma unroll
      for (int r = 0; r < 16; r++) {
        const float v = (sa0[r] + sa1[r]) * SCALE2;
        sv[r] = v;
        mx = fmaxf(mx, v);
      }
    }
    mx = fmaxf(mx, __shfl_xor(mx, 32));
    float mref = m_run;
    float alpha = 1.0f;
    const bool resc = !__all(mx <= m_run + 11.5f);  // defer-max (T13)
    if (resc) {
      mref = fmaxf(m_run, mx);
      alpha = exp2f(m_run - mref);
      m_run = mref;
    }
    float psum = 0.0f;
    unsigned pw[8];
    #pragma unroll
    for (int t = 0; t < 8; t++) {
      const float p0 = exp2f(sv[2 * t] - mref);
      const float p1 = exp2f(sv[2 * t + 1] - mref);
      psum += p0 + p1;
      pw[t] = cvt_pk_bf16(p0, p1);
    }
    psum += __shfl_xor(psum, 32);
    l_run = l_run * alpha + psum;
    if (resc) {
      #pragma unroll
      for (int r = 0; r < 16; r++) {
        const int row = (r & 3) + 8 * (r >> 2) + 4 * hi;
        const float a = __shfl(alpha, row);
        ya0[r] *= a;
        ya1[r] *= a;
      }
    }
    // --- PV: redistribute P via permlane32_swap, then MFMA ---
    #pragma unroll
    for (int s = 0; s < 2; s++) {
      unsigned a0 = pw[4 * s],     b0 = pw[4 * s + 2];
      unsigned a1 = pw[4 * s + 1], b1 = pw[4 * s + 3];
      asm volatile("v_permlane32_swap_b32 %0, %1" : "+v"(a0), "+v"(b0));
      asm volatile("v_permlane32_swap_b32 %0, %1" : "+v"(a1), "+v"(b1));
      u32x4 t4;
      t4[0] = a0; t4[1] = a1; t4[2] = b0; t4[3] = b1;
      const bf16x8 pf = __builtin_bit_cast(bf16x8, t4);
      __builtin_amdgcn_s_setprio(1);
      ya0 = __builtin_amdgcn_mfma_f32_32x32x16_bf16(pf, vc[s * 2],     ya0, 0, 0, 0);
      ya1 = __builtin_amdgcn_mfma_f32_32x32x16_bf16(pf, vc[s * 2 + 1], ya1, 0, 0, 0);
      __builtin_amdgcn_s_setprio(0);
    }
  }
  // --- write partials: m, l per row; unnormalized Y (bf16) ---
  if (hi == 0) {
    mpart[(size_t)task * 32 + li] = m_run;
    lpart[(size_t)task * 32 + li] = l_run;
  }
  short* yb = Ypart + (size_t)task * 2048;
  #pragma unroll
  for (int r = 0; r < 16; r++) {
    const int row = (r & 3) + 8 * (r >> 2) + 4 * hi;
    yb[row * 64 + li]      = f2bf(ya0[r]);
    yb[row * 64 + 32 + li] = f2bf(ya1[r]);
  }
}

// ---------------- attention combine: merge <=8 chunks (c-major layout) ------
__global__ __launch_bounds__(256) void attn_combine(
    const float* __restrict__ mpart, const float* __restrict__ lpart,
    const short* __restrict__ Ypart, short* __restrict__ yout) {
  const int blk = blockIdx.x;  // bh*32 + it
  const int it = blk & 31, bh = blk >> 5;
  const int b = bh / 12, h = bh % 12;
  const int g = it >> 2;
  const int nc = g + 1;
  const int row = threadIdx.x >> 3;
  const int c0 = (threadIdx.x & 7) * 8;
  // chunk cI lives at task index bh*144 + it + 30*cI - 2*cI*cI
  float mv[8], lv[8], wgt[8];
  float m = -1e30f;
  #pragma unroll
  for (int cI = 0; cI < 8; ++cI) {
    const int idx = bh * 144 + it + 30 * cI - 2 * cI * cI;
    mv[cI] = (cI < nc) ? mpart[(size_t)idx * 32 + row] : -1e30f;
    lv[cI] = (cI < nc) ? lpart[(size_t)idx * 32 + row] : 0.0f;
    m = fmaxf(m, mv[cI]);
  }
  float L = 0.0f;
  #pragma unroll
  for (int cI = 0; cI < 8; ++cI) {
    wgt[cI] = exp2f(mv[cI] - m);
    L += lv[cI] * wgt[cI];
  }
  const float inv = 1.0f / L;
  float y[8];
  #pragma unroll
  for (int r = 0; r < 8; r++) y[r] = 0.0f;
  #pragma unroll
  for (int cI = 0; cI < 8; ++cI) {
    if (cI < nc) {
      const int idx = bh * 144 + it + 30 * cI - 2 * cI * cI;
      bf16x8 v = *(const bf16x8*)(Ypart + ((size_t)idx * 32 + row) * 64 + c0);
      #pragma unroll
      for (int r = 0; r < 8; r++) y[r] += bf2f(v[r]) * wgt[cI];
    }
  }
  short* dst = yout + (size_t)(b * 1024 + it * 32 + row) * 768 + h * 64 + c0;
  #pragma unroll
  for (int r = 0; r < 8; r++) dst[r] = f2bf(y[r] * inv);
}

// ---------------- launch ----------------
extern "C" void kernel_launch(void* const* d_in, const int* in_sizes, int n_in,
                              void* d_out, int out_size, void* d_ws, size_t ws_size,
                              hipStream_t stream) {
  const float* x       = (const float*)d_in[0];
  const float* ln1_w   = (const float*)d_in[1];
  const float* w_attn  = (const float*)d_in[2];
  // d_in[3] = w_pos (dead code in reference)
  const float* w_cproj = (const float*)d_in[4];
  const float* ln2_w   = (const float*)d_in[5];
  const float* w_fc    = (const float*)d_in[6];
  const float* w_mproj = (const float*)d_in[7];
  float* out = (float*)d_out;
  char* ws = (char*)d_ws;

  short* wT_attn  = (short*)(ws + 0);          // [2304][768]
  short* wT_cproj = (short*)(ws + 3538944);    // [768][768]
  short* wT_fc    = (short*)(ws + 4718592);    // [3072][768]
  short* wT_mproj = (short*)(ws + 9437184);    // [768][3072]
  short* ktab     = (short*)(ws + 14155776);   // [1024][64] bf16 (128KB)
  short* h_bf     = (short*)(ws + 14417920);   // [4096][768]; reused as qpr
  short* qpr      = (short*)(ws + 14417920);   // [48*1024][64] (h_bf dead then)
  short* qkv_bf   = (short*)(ws + 20709376);   // [4096][2304]
  short* vT       = (short*)(ws + 39583744);   // [48][64][1024]
  short* y_att    = (short*)(ws + 45875200);   // [4096][768]
  short* h2_bf    = (short*)(ws + 52166656);   // [4096][768]
  short* hfc_bf   = (short*)(ws + 58458112);   // [4096][3072]
  // attention partials alias the (not-yet-live) MLP buffers:
  float* mpart = (float*)(ws + 52166656);      // [6912][32] f32
  float* lpart = (float*)(ws + 53051392);      // [6912][32] f32
  short* Ypart = (short*)(ws + 53936128);      // [6912][32][64] bf16 (28.3MB)
  // mproj split-K=2 partials alias dead qkv_bf+vT: 2 x [4096][768] f32
  float* Cpart = (float*)(ws + 20709376);      // 25165824 B exactly

  // weight prep
  wtrans_all<<<6912, 256, 0, stream>>>(w_attn, w_cproj, w_fc, w_mproj,
                                       wT_attn, wT_cproj, wT_fc, wT_mproj);

  // attention branch
  ln_kernel<<<4096, 256, 0, stream>>>(x, ln1_w, h_bf);
  gemm_bt<0, 128, 128><<<dim3(18, 32), 256, 0, stream>>>(
      h_bf, wT_attn, nullptr, nullptr, qkv_bf, 4096, 2304, 768, 768, 768);
  qprime_kernel<<<6144, 256, 0, stream>>>(qkv_bf, qpr, ktab);
  vtrans_kernel<<<768, 256, 0, stream>>>(qkv_bf, vT);
  attn_part8<<<864, 512, 0, stream>>>(qkv_bf, vT, qpr, ktab, mpart, lpart, Ypart);
  attn_combine<<<1536, 256, 0, stream>>>(mpart, lpart, Ypart, y_att);
  gemm_bt<1, 64, 64><<<dim3(12, 64), 256, 0, stream>>>(
      y_att, wT_cproj, x, out, nullptr, 4096, 768, 768, 768, 768);
  // MLP branch
  ln_kernel<<<4096, 256, 0, stream>>>(out, ln2_w, h2_bf);
  gemm_bt<2, 128, 128><<<dim3(24, 32), 256, 0, stream>>>(
      h2_bf, wT_fc, nullptr, nullptr, hfc_bf, 4096, 3072, 768, 768, 768);
  // mproj: split-K=2 (qkv_bf/vT are dead by now; Cpart aliases them)
  gemm_bt<3, 128, 64><<<dim3(12, 32, 2), 256, 0, stream>>>(
      hfc_bf, wT_mproj, nullptr, Cpart, nullptr, 4096, 768, 1536, 3072, 3072);
  reduce_splitk<<<3072, 256, 0, stream>>>(Cpart, out, out);
}

// Round 7
// 207.980 us; speedup vs baseline: 1.2036x; 1.0970x over previous
//
#include <hip/hip_runtime.h>
#include <math.h>

typedef __attribute__((ext_vector_type(8))) short bf16x8;
typedef __attribute__((ext_vector_type(4))) float f32x4;
typedef __attribute__((ext_vector_type(16))) float f32x16;
typedef __attribute__((ext_vector_type(4))) unsigned u32x4;

__device__ inline short f2bf(float f) {
  unsigned u = __builtin_bit_cast(unsigned, f);
  u = u + 0x7fffu + ((u >> 16) & 1u);
  return (short)(u >> 16);
}
__device__ inline float bf2f(short s) {
  return __builtin_bit_cast(float, ((unsigned)(unsigned short)s) << 16);
}
__device__ inline unsigned cvt_pk_bf16(float lo, float hi) {
  unsigned r;
  asm("v_cvt_pk_bf16_f32 %0, %1, %2" : "=v"(r) : "v"(lo), "v"(hi));
  return r;
}

// async global->LDS, 16B per lane. lds base must be wave-uniform.
__device__ inline void gload16(const short* g, short* l) {
  __builtin_amdgcn_global_load_lds(
      (const __attribute__((address_space(1))) unsigned*)g,
      (__attribute__((address_space(3))) unsigned*)l, 16, 0, 0);
}

// ---------------- all four weight transposes fp32[K,N] -> bf16[N,K] ---------
__global__ __launch_bounds__(256) void wtrans_all(
    const float* __restrict__ wa, const float* __restrict__ wc,
    const float* __restrict__ wf, const float* __restrict__ wm,
    short* __restrict__ oa, short* __restrict__ oc,
    short* __restrict__ of, short* __restrict__ om) {
  __shared__ float tile[32][33];
  int blk = blockIdx.x;
  const float* in; short* out; int K, N, bx;
  if (blk < 1728)      { in = wa; out = oa; K = 768;  N = 2304; bx = 72; }
  else if (blk < 2304) { blk -= 1728; in = wc; out = oc; K = 768;  N = 768;  bx = 24; }
  else if (blk < 4608) { blk -= 2304; in = wf; out = of; K = 768;  N = 3072; bx = 96; }
  else                 { blk -= 4608; in = wm; out = om; K = 3072; N = 768;  bx = 24; }
  const int n0 = (blk % bx) * 32, k0 = (blk / bx) * 32;
  const int tx = threadIdx.x & 31, ty = threadIdx.x >> 5;
  #pragma unroll
  for (int r = ty; r < 32; r += 8)
    tile[r][tx] = in[(size_t)(k0 + r) * N + n0 + tx];
  __syncthreads();
  #pragma unroll
  for (int r = ty; r < 32; r += 8)
    out[(size_t)(n0 + r) * K + k0 + tx] = f2bf(tile[tx][r]);
}

// ---------------- Q' from q (angle-sum folding of rpe) + ktab (bh==0) -------
__global__ __launch_bounds__(256) void qprime_kernel(
    const short* __restrict__ qkv, short* __restrict__ qpr,
    short* __restrict__ ktab) {
  const int idx = blockIdx.x * 256 + threadIdx.x;  // 48*1024*32
  const int cc = idx & 31;
  const int row = idx >> 5;            // bh*1024 + i
  const int i = row & 1023, bh = row >> 10;
  const int b = bh / 12, h = bh % 12;
  const float invf = exp2f(-(float)cc * (13.287712379549449f / 32.0f));
  const float ang = (float)i * invf;
  float si, co;
  __sincosf(ang, &si, &co);
  if (bh == 0) {
    ktab[i * 64 + cc]      = f2bf(co);
    ktab[i * 64 + 32 + cc] = f2bf(si);
  }
  const short* q = qkv + (size_t)(b * 1024 + i) * 2304 + h * 64;
  const float qs = bf2f(q[cc]), qc = bf2f(q[32 + cc]);
  qpr[(size_t)row * 64 + cc]      = f2bf(qs * si + qc * co);
  qpr[(size_t)row * 64 + 32 + cc] = f2bf(qc * si - qs * co);
}

// ---------------- LayerNorm fp32 row(768) -> bf16 ----------------
__global__ __launch_bounds__(256) void ln_kernel(
    const float* __restrict__ x, const float* __restrict__ w,
    short* __restrict__ out) {
  const int row = blockIdx.x, tid = threadIdx.x;
  const float* xr = x + (size_t)row * 768;
  float v0 = xr[tid], v1 = xr[tid + 256], v2 = xr[tid + 512];
  float s = v0 + v1 + v2;
  #pragma unroll
  for (int o = 1; o < 64; o <<= 1) s += __shfl_xor(s, o);
  __shared__ float red[8];
  const int wv = tid >> 6;
  if ((tid & 63) == 0) red[wv] = s;
  __syncthreads();
  const float mean = (red[0] + red[1] + red[2] + red[3]) * (1.0f / 768.0f);
  v0 -= mean; v1 -= mean; v2 -= mean;
  float q = v0 * v0 + v1 * v1 + v2 * v2;
  #pragma unroll
  for (int o = 1; o < 64; o <<= 1) q += __shfl_xor(q, o);
  if ((tid & 63) == 0) red[4 + wv] = q;
  __syncthreads();
  const float var = (red[4] + red[5] + red[6] + red[7]) * (1.0f / 768.0f);
  const float inv = 1.0f / sqrtf(var + 1e-5f);
  out[(size_t)row * 768 + tid]       = f2bf(v0 * inv * w[tid]);
  out[(size_t)row * 768 + tid + 256] = f2bf(v1 * inv * w[tid + 256]);
  out[(size_t)row * 768 + tid + 512] = f2bf(v2 * inv * w[tid + 512]);
}

// ---------------- V transpose: qkv v-part -> vT[b,h,d,t] ----------------
__global__ __launch_bounds__(256) void vtrans_kernel(
    const short* __restrict__ qkv, short* __restrict__ vT) {
  __shared__ short tile[64][65];
  const int blk = blockIdx.x;
  const int bh = blk >> 4, t0 = (blk & 15) * 64;
  const int b = bh / 12, h = bh % 12;
  const int tx = threadIdx.x & 63, ty = threadIdx.x >> 6;
  const short* src = qkv + (size_t)(b * 1024 + t0) * 2304 + 1536 + h * 64;
  #pragma unroll
  for (int r = ty; r < 64; r += 4)
    tile[r][tx] = src[(size_t)r * 2304 + tx];
  __syncthreads();
  short* dst = vT + (size_t)bh * 64 * 1024 + t0;
  #pragma unroll
  for (int r = ty; r < 64; r += 4)
    dst[(size_t)r * 1024 + tx] = tile[tx][r];
}

// ---------------- GEMM: C[M,N] = A[M,K](bf16) x Bt[N,K](bf16) ----------------
// 2-phase double-buffered global_load_lds staging; ONE barrier per K-step.
// EPI 0: bf16 store  1: f32 out=res+acc  2: bf16 gelu  3: f32 split-K partial
template <int EPI, int BM, int BN>
__global__ __launch_bounds__(256) void gemm_bt(
    const short* __restrict__ A, const short* __restrict__ Bt,
    const float* __restrict__ res, float* __restrict__ outF,
    short* __restrict__ outB, int M, int N, int K, int lda, int ldb) {
  __shared__ __align__(16) short As[2][BM * 32];
  __shared__ __align__(16) short Bs[2][BN * 32];
  constexpr int WM = BM / 2, WN = BN / 2;
  constexpr int MI = WM / 16, NJ = WN / 16;
  const int tid = threadIdx.x;
  const int w = tid >> 6, lane = tid & 63;
  const int m0 = blockIdx.y * BM, n0 = blockIdx.x * BN;
  const int wm = (w >> 1) * WM, wn = (w & 1) * WN;
  const int lr = lane >> 2;
  const int lc = (lane & 3) * 8;
  if constexpr (EPI == 3) {
    A += (size_t)blockIdx.z * K;
    Bt += (size_t)blockIdx.z * K;
    outF += (size_t)blockIdx.z * M * N;
  }
  f32x4 acc[MI][NJ];
  #pragma unroll
  for (int i = 0; i < MI; i++)
    #pragma unroll
    for (int j = 0; j < NJ; j++)
      #pragma unroll
      for (int r = 0; r < 4; r++) acc[i][j][r] = 0.0f;

  const int nt = K / 32;
  // prologue stage into buf 0
  #pragma unroll
  for (int p = 0; p < BM / 64; ++p)
    gload16(A + (size_t)(m0 + p * 64 + w * 16 + lr) * lda + lc,
            &As[0][p * 2048 + w * 512]);
  #pragma unroll
  for (int p = 0; p < BN / 64; ++p)
    gload16(Bt + (size_t)(n0 + p * 64 + w * 16 + lr) * ldb + lc,
            &Bs[0][p * 2048 + w * 512]);
  __syncthreads();

  for (int t = 0; t < nt; ++t) {
    const int cur = t & 1;
    if (t + 1 < nt) {
      const int kt = (t + 1) * 32;
      #pragma unroll
      for (int p = 0; p < BM / 64; ++p)
        gload16(A + (size_t)(m0 + p * 64 + w * 16 + lr) * lda + kt + lc,
                &As[cur ^ 1][p * 2048 + w * 512]);
      #pragma unroll
      for (int p = 0; p < BN / 64; ++p)
        gload16(Bt + (size_t)(n0 + p * 64 + w * 16 + lr) * ldb + kt + lc,
                &Bs[cur ^ 1][p * 2048 + w * 512]);
    }
    bf16x8 af[MI], bfr[NJ];
    #pragma unroll
    for (int i = 0; i < MI; i++)
      af[i] = *(const bf16x8*)&As[cur][(wm + i * 16 + (lane & 15)) * 32 + (lane >> 4) * 8];
    #pragma unroll
    for (int j = 0; j < NJ; j++)
      bfr[j] = *(const bf16x8*)&Bs[cur][(wn + j * 16 + (lane & 15)) * 32 + (lane >> 4) * 8];
    #pragma unroll
    for (int i = 0; i < MI; i++)
      #pragma unroll
      for (int j = 0; j < NJ; j++)
        acc[i][j] = __builtin_amdgcn_mfma_f32_16x16x32_bf16(af[i], bfr[j],
                                                            acc[i][j], 0, 0, 0);
    __syncthreads();
  }
  const int r0 = (lane >> 4) * 4, cl = lane & 15;
  #pragma unroll
  for (int i = 0; i < MI; i++) {
    #pragma unroll
    for (int j = 0; j < NJ; j++) {
      const int gm = m0 + wm + i * 16 + r0;
      const int gn = n0 + wn + j * 16 + cl;
      #pragma unroll
      for (int r = 0; r < 4; r++) {
        const size_t idx = (size_t)(gm + r) * N + gn;
        const float v = acc[i][j][r];
        if constexpr (EPI == 0) {
          outB[idx] = f2bf(v);
        } else if constexpr (EPI == 1) {
          outF[idx] = res[idx] + v;
        } else if constexpr (EPI == 2) {
          outB[idx] = f2bf(0.5f * v * (1.0f + erff(v * 0.70710678118f)));
        } else {
          outF[idx] = v;
        }
      }
    }
  }
}

// ---------------- split-K=2 reduce: out = res + sum_z Cp[z] ----------------
__global__ __launch_bounds__(256) void reduce_splitk(
    const float* __restrict__ Cp, const float* __restrict__ res,
    float* __restrict__ out) {
  const size_t i4 = ((size_t)blockIdx.x * 256 + threadIdx.x) * 4;
  float4 a = *(const float4*)(res + i4);
  #pragma unroll
  for (int z = 0; z < 2; ++z) {
    float4 p = *(const float4*)(Cp + (size_t)z * 3145728 + i4);
    a.x += p.x; a.y += p.y; a.z += p.z; a.w += p.w;
  }
  *(float4*)(out + i4) = a;
}

// ---------------- attention partials: cooperative LDS-staged j-window -------
// block = (bh, window c, sub). All 8 waves share the SAME 4-tile j-window
// [4c, 4c+3]; wave w owns it = 4c + sub*8 + w (idle if it>31; diag waves stop
// at jt=it). Kaug(K||ktab) and V staged in LDS, double-buffered, async split.
// Task index (R6-compatible): task = bh*144 + it + 30c - 2c^2.
__global__ __launch_bounds__(512) void attn_part8(
    const short* __restrict__ qkv, const short* __restrict__ vT,
    const short* __restrict__ qpr, const short* __restrict__ ktab,
    float* __restrict__ mpart, float* __restrict__ lpart,
    short* __restrict__ Ypart) {
  __shared__ __align__(16) short Ka[2][32 * 136];  // row: [k(64) | ktab(64) | pad8]
  __shared__ __align__(16) short Va[2][64 * 40];   // row d: [v(32) | pad8]
  const int bx = blockIdx.x;
  const int bh = bx / 20;
  const int r = bx % 20;
  int c, sub;
  if (r < 4)        { c = 0; sub = r; }
  else if (r < 8)   { c = 1; sub = r - 4; }
  else if (r < 11)  { c = 2; sub = r - 8; }
  else if (r < 14)  { c = 3; sub = r - 11; }
  else if (r < 16)  { c = 4; sub = r - 14; }
  else if (r < 18)  { c = 5; sub = r - 16; }
  else if (r == 18) { c = 6; sub = 0; }
  else              { c = 7; sub = 0; }
  const int tid = threadIdx.x;
  const int w = tid >> 6;
  const int lane = tid & 63;
  const int li = lane & 31, hi = lane >> 5;
  const int it = 4 * c + sub * 8 + w;
  const bool valid = (it <= 31);
  const int b = bh / 12, h = bh % 12;
  const int I0 = (valid ? it : 31) * 32;
  const int jt0 = 4 * c;
  const int jtmax = valid ? ((it < jt0 + 3) ? it : jt0 + 3) : (jt0 - 1);
  constexpr float SCALE2 = 0.125f * 1.44269504089f;  // 1/sqrt(64) * log2(e)

  const short* kbase = qkv + (size_t)(b * 1024) * 2304 + 768 + h * 64;
  const short* vbase = vT + (size_t)bh * 64 * 1024;

  // staging roles: Kaug = 32 rows x 256B = 512 x 16B chunks (1/thread);
  // V = 64 rows x 64B = 256 chunks (threads 0..255).
  const int krow = tid >> 4, kch = tid & 15;
  const short* ksrc = (kch < 8) ? (kbase + kch * 8) : (ktab + (kch - 8) * 8);
  const size_t kstr = (kch < 8) ? 2304 : 64;
  const int vrow = tid >> 2, vch = tid & 3;

  int4 kreg, vreg;
  {
    const int J0 = jt0 * 32;
    kreg = *(const int4*)(ksrc + (size_t)(J0 + krow) * kstr);
    if (tid < 256)
      vreg = *(const int4*)(vbase + (size_t)vrow * 1024 + J0 + vch * 8);
  }

  // Qaug fragments: [q(64) | Q'(64)] (clamped row for idle waves)
  const short* qrow = qkv + (size_t)(b * 1024 + I0 + li) * 2304 + h * 64;
  const short* qprow = qpr + ((size_t)bh * 1024 + I0 + li) * 64;
  bf16x8 qf[8];
  #pragma unroll
  for (int s = 0; s < 4; s++) {
    qf[s]     = *(const bf16x8*)(qrow + s * 16 + hi * 8);
    qf[4 + s] = *(const bf16x8*)(qprow + s * 16 + hi * 8);
  }

  *(int4*)&Ka[0][krow * 136 + kch * 8] = kreg;
  if (tid < 256) *(int4*)&Va[0][vrow * 40 + vch * 8] = vreg;
  __syncthreads();

  float m_run = -1e30f, l_run = 0.0f;
  f32x16 ya0, ya1;
  #pragma unroll
  for (int q = 0; q < 16; q++) { ya0[q] = 0.0f; ya1[q] = 0.0f; }

  for (int t = 0; t < 4; ++t) {
    const int cur = t & 1;
    // async-stage split: issue next tile's global loads before compute
    if (t < 3) {
      const int J0n = (jt0 + t + 1) * 32;
      kreg = *(const int4*)(ksrc + (size_t)(J0n + krow) * kstr);
      if (tid < 256)
        vreg = *(const int4*)(vbase + (size_t)vrow * 1024 + J0n + vch * 8);
    }
    const int jt = jt0 + t;
    if (jt <= jtmax) {
      // fragments from LDS
      bf16x8 kf[8];
      #pragma unroll
      for (int s = 0; s < 8; s++)
        kf[s] = *(const bf16x8*)&Ka[cur][li * 136 + s * 16 + hi * 8];
      bf16x8 vc[4];
      #pragma unroll
      for (int s = 0; s < 2; s++) {
        vc[s * 2]     = *(const bf16x8*)&Va[cur][li * 40 + s * 16 + hi * 8];
        vc[s * 2 + 1] = *(const bf16x8*)&Va[cur][(32 + li) * 40 + s * 16 + hi * 8];
      }
      // --- S^T = Kaug . Qaug^T, two independent chains ---
      f32x16 sa0, sa1;
      #pragma unroll
      for (int q = 0; q < 16; q++) { sa0[q] = 0.0f; sa1[q] = 0.0f; }
      __builtin_amdgcn_s_setprio(1);
      #pragma unroll
      for (int s = 0; s < 4; s++) {
        sa0 = __builtin_amdgcn_mfma_f32_32x32x16_bf16(kf[2 * s],     qf[2 * s],     sa0, 0, 0, 0);
        sa1 = __builtin_amdgcn_mfma_f32_32x32x16_bf16(kf[2 * s + 1], qf[2 * s + 1], sa1, 0, 0, 0);
      }
      __builtin_amdgcn_s_setprio(0);
      // --- scale (log2 domain), mask only diagonal tile, online softmax ---
      float sv[16];
      float mx = -1e30f;
      if (jt == it) {
        #pragma unroll
        for (int q = 0; q < 16; q++) {
          const int j = (q & 3) + 8 * (q >> 2) + 4 * hi;
          float v = (sa0[q] + sa1[q]) * SCALE2;
          v = (j <= li) ? v : -1e30f;
          sv[q] = v;
          mx = fmaxf(mx, v);
        }
      } else {
        #pragma unroll
        for (int q = 0; q < 16; q++) {
          const float v = (sa0[q] + sa1[q]) * SCALE2;
          sv[q] = v;
          mx = fmaxf(mx, v);
        }
      }
      mx = fmaxf(mx, __shfl_xor(mx, 32));
      float mref = m_run;
      float alpha = 1.0f;
      const bool resc = !__all(mx <= m_run + 11.5f);  // defer-max (T13)
      if (resc) {
        mref = fmaxf(m_run, mx);
        alpha = exp2f(m_run - mref);
        m_run = mref;
      }
      float psum = 0.0f;
      unsigned pw[8];
      #pragma unroll
      for (int q = 0; q < 8; q++) {
        const float p0 = exp2f(sv[2 * q] - mref);
        const float p1 = exp2f(sv[2 * q + 1] - mref);
        psum += p0 + p1;
        pw[q] = cvt_pk_bf16(p0, p1);
      }
      psum += __shfl_xor(psum, 32);
      l_run = l_run * alpha + psum;
      if (resc) {
        #pragma unroll
        for (int q = 0; q < 16; q++) {
          const int row = (q & 3) + 8 * (q >> 2) + 4 * hi;
          const float a = __shfl(alpha, row);
          ya0[q] *= a;
          ya1[q] *= a;
        }
      }
      // --- PV: redistribute P via permlane32_swap, then MFMA ---
      #pragma unroll
      for (int s = 0; s < 2; s++) {
        unsigned a0 = pw[4 * s],     b0 = pw[4 * s + 2];
        unsigned a1 = pw[4 * s + 1], b1 = pw[4 * s + 3];
        asm volatile("v_permlane32_swap_b32 %0, %1" : "+v"(a0), "+v"(b0));
        asm volatile("v_permlane32_swap_b32 %0, %1" : "+v"(a1), "+v"(b1));
        u32x4 t4;
        t4[0] = a0; t4[1] = a1; t4[2] = b0; t4[3] = b1;
        const bf16x8 pf = __builtin_bit_cast(bf16x8, t4);
        __builtin_amdgcn_s_setprio(1);
        ya0 = __builtin_amdgcn_mfma_f32_32x32x16_bf16(pf, vc[s * 2],     ya0, 0, 0, 0);
        ya1 = __builtin_amdgcn_mfma_f32_32x32x16_bf16(pf, vc[s * 2 + 1], ya1, 0, 0, 0);
        __builtin_amdgcn_s_setprio(0);
      }
    }
    // write next buffer (other buffer than the one being read this iter)
    if (t < 3) {
      *(int4*)&Ka[cur ^ 1][krow * 136 + kch * 8] = kreg;
      if (tid < 256) *(int4*)&Va[cur ^ 1][vrow * 40 + vch * 8] = vreg;
    }
    __syncthreads();
  }
  if (!valid) return;
  // --- write partials: m, l per row; unnormalized Y (bf16) ---
  const int task = bh * 144 + it + 30 * c - 2 * c * c;
  if (hi == 0) {
    mpart[(size_t)task * 32 + li] = m_run;
    lpart[(size_t)task * 32 + li] = l_run;
  }
  short* yb = Ypart + (size_t)task * 2048;
  #pragma unroll
  for (int q = 0; q < 16; q++) {
    const int row = (q & 3) + 8 * (q >> 2) + 4 * hi;
    yb[row * 64 + li]      = f2bf(ya0[q]);
    yb[row * 64 + 32 + li] = f2bf(ya1[q]);
  }
}

// ---------------- attention combine: merge <=8 chunks (c-major layout) ------
__global__ __launch_bounds__(256) void attn_combine(
    const float* __restrict__ mpart, const float* __restrict__ lpart,
    const short* __restrict__ Ypart, short* __restrict__ yout) {
  const int blk = blockIdx.x;  // bh*32 + it
  const int it = blk & 31, bh = blk >> 5;
  const int b = bh / 12, h = bh % 12;
  const int g = it >> 2;
  const int nc = g + 1;
  const int row = threadIdx.x >> 3;
  const int c0 = (threadIdx.x & 7) * 8;
  // chunk cI lives at task index bh*144 + it + 30*cI - 2*cI*cI
  float mv[8], lv[8], wgt[8];
  float m = -1e30f;
  #pragma unroll
  for (int cI = 0; cI < 8; ++cI) {
    const int idx = bh * 144 + it + 30 * cI - 2 * cI * cI;
    mv[cI] = (cI < nc) ? mpart[(size_t)idx * 32 + row] : -1e30f;
    lv[cI] = (cI < nc) ? lpart[(size_t)idx * 32 + row] : 0.0f;
    m = fmaxf(m, mv[cI]);
  }
  float L = 0.0f;
  #pragma unroll
  for (int cI = 0; cI < 8; ++cI) {
    wgt[cI] = exp2f(mv[cI] - m);
    L += lv[cI] * wgt[cI];
  }
  const float inv = 1.0f / L;
  float y[8];
  #pragma unroll
  for (int r = 0; r < 8; r++) y[r] = 0.0f;
  #pragma unroll
  for (int cI = 0; cI < 8; ++cI) {
    if (cI < nc) {
      const int idx = bh * 144 + it + 30 * cI - 2 * cI * cI;
      bf16x8 v = *(const bf16x8*)(Ypart + ((size_t)idx * 32 + row) * 64 + c0);
      #pragma unroll
      for (int r = 0; r < 8; r++) y[r] += bf2f(v[r]) * wgt[cI];
    }
  }
  short* dst = yout + (size_t)(b * 1024 + it * 32 + row) * 768 + h * 64 + c0;
  #pragma unroll
  for (int r = 0; r < 8; r++) dst[r] = f2bf(y[r] * inv);
}

// ---------------- launch ----------------
extern "C" void kernel_launch(void* const* d_in, const int* in_sizes, int n_in,
                              void* d_out, int out_size, void* d_ws, size_t ws_size,
                              hipStream_t stream) {
  const float* x       = (const float*)d_in[0];
  const float* ln1_w   = (const float*)d_in[1];
  const float* w_attn  = (const float*)d_in[2];
  // d_in[3] = w_pos (dead code in reference)
  const float* w_cproj = (const float*)d_in[4];
  const float* ln2_w   = (const float*)d_in[5];
  const float* w_fc    = (const float*)d_in[6];
  const float* w_mproj = (const float*)d_in[7];
  float* out = (float*)d_out;
  char* ws = (char*)d_ws;

  short* wT_attn  = (short*)(ws + 0);          // [2304][768]
  short* wT_cproj = (short*)(ws + 3538944);    // [768][768]
  short* wT_fc    = (short*)(ws + 4718592);    // [3072][768]
  short* wT_mproj = (short*)(ws + 9437184);    // [768][3072]
  short* ktab     = (short*)(ws + 14155776);   // [1024][64] bf16 (128KB)
  short* h_bf     = (short*)(ws + 14417920);   // [4096][768]; reused as qpr
  short* qpr      = (short*)(ws + 14417920);   // [48*1024][64] (h_bf dead then)
  short* qkv_bf   = (short*)(ws + 20709376);   // [4096][2304]
  short* vT       = (short*)(ws + 39583744);   // [48][64][1024]
  short* y_att    = (short*)(ws + 45875200);   // [4096][768]
  short* h2_bf    = (short*)(ws + 52166656);   // [4096][768]
  short* hfc_bf   = (short*)(ws + 58458112);   // [4096][3072]
  // attention partials alias the (not-yet-live) MLP buffers:
  float* mpart = (float*)(ws + 52166656);      // [6912][32] f32
  float* lpart = (float*)(ws + 53051392);      // [6912][32] f32
  short* Ypart = (short*)(ws + 53936128);      // [6912][32][64] bf16 (28.3MB)
  // mproj split-K=2 partials alias dead qkv_bf+vT: 2 x [4096][768] f32
  float* Cpart = (float*)(ws + 20709376);      // 25165824 B exactly

  // weight prep
  wtrans_all<<<6912, 256, 0, stream>>>(w_attn, w_cproj, w_fc, w_mproj,
                                       wT_attn, wT_cproj, wT_fc, wT_mproj);

  // attention branch
  ln_kernel<<<4096, 256, 0, stream>>>(x, ln1_w, h_bf);
  gemm_bt<0, 128, 128><<<dim3(18, 32), 256, 0, stream>>>(
      h_bf, wT_attn, nullptr, nullptr, qkv_bf, 4096, 2304, 768, 768, 768);
  qprime_kernel<<<6144, 256, 0, stream>>>(qkv_bf, qpr, ktab);
  vtrans_kernel<<<768, 256, 0, stream>>>(qkv_bf, vT);
  attn_part8<<<960, 512, 0, stream>>>(qkv_bf, vT, qpr, ktab, mpart, lpart, Ypart);
  attn_combine<<<1536, 256, 0, stream>>>(mpart, lpart, Ypart, y_att);
  gemm_bt<1, 64, 64><<<dim3(12, 64), 256, 0, stream>>>(
      y_att, wT_cproj, x, out, nullptr, 4096, 768, 768, 768, 768);
  // MLP branch
  ln_kernel<<<4096, 256, 0, stream>>>(out, ln2_w, h2_bf);
  gemm_bt<2, 128, 128><<<dim3(24, 32), 256, 0, stream>>>(
      h2_bf, wT_fc, nullptr, nullptr, hfc_bf, 4096, 3072, 768, 768, 768);
  // mproj: split-K=2 (qkv_bf/vT are dead by now; Cpart aliases them)
  gemm_bt<3, 128, 64><<<dim3(12, 32, 2), 256, 0, stream>>>(
      hfc_bf, wT_mproj, nullptr, Cpart, nullptr, 4096, 768, 1536, 3072, 3072);
  reduce_splitk<<<3072, 256, 0, stream>>>(Cpart, out, out);
}

// Round 8
// 200.673 us; speedup vs baseline: 1.2474x; 1.0364x over previous
//
#include <hip/hip_runtime.h>
#include <math.h>

typedef __attribute__((ext_vector_type(8))) short bf16x8;
typedef __attribute__((ext_vector_type(4))) float f32x4;
typedef __attribute__((ext_vector_type(16))) float f32x16;
typedef __attribute__((ext_vector_type(4))) unsigned u32x4;

__device__ inline short f2bf(float f) {
  unsigned u = __builtin_bit_cast(unsigned, f);
  u = u + 0x7fffu + ((u >> 16) & 1u);
  return (short)(u >> 16);
}
__device__ inline float bf2f(short s) {
  return __builtin_bit_cast(float, ((unsigned)(unsigned short)s) << 16);
}
__device__ inline unsigned cvt_pk_bf16(float lo, float hi) {
  unsigned r;
  asm("v_cvt_pk_bf16_f32 %0, %1, %2" : "=v"(r) : "v"(lo), "v"(hi));
  return r;
}

// async global->LDS, 16B per lane. lds base must be wave-uniform.
__device__ inline void gload16(const short* g, short* l) {
  __builtin_amdgcn_global_load_lds(
      (const __attribute__((address_space(1))) unsigned*)g,
      (__attribute__((address_space(3))) unsigned*)l, 16, 0, 0);
}

// ---------------- all four weight transposes fp32[K,N] -> bf16[N,K] ---------
__global__ __launch_bounds__(256) void wtrans_all(
    const float* __restrict__ wa, const float* __restrict__ wc,
    const float* __restrict__ wf, const float* __restrict__ wm,
    short* __restrict__ oa, short* __restrict__ oc,
    short* __restrict__ of, short* __restrict__ om) {
  __shared__ float tile[32][33];
  int blk = blockIdx.x;
  const float* in; short* out; int K, N, bx;
  if (blk < 1728)      { in = wa; out = oa; K = 768;  N = 2304; bx = 72; }
  else if (blk < 2304) { blk -= 1728; in = wc; out = oc; K = 768;  N = 768;  bx = 24; }
  else if (blk < 4608) { blk -= 2304; in = wf; out = of; K = 768;  N = 3072; bx = 96; }
  else                 { blk -= 4608; in = wm; out = om; K = 3072; N = 768;  bx = 24; }
  const int n0 = (blk % bx) * 32, k0 = (blk / bx) * 32;
  const int tx = threadIdx.x & 31, ty = threadIdx.x >> 5;
  #pragma unroll
  for (int r = ty; r < 32; r += 8)
    tile[r][tx] = in[(size_t)(k0 + r) * N + n0 + tx];
  __syncthreads();
  #pragma unroll
  for (int r = ty; r < 32; r += 8)
    out[(size_t)(n0 + r) * K + k0 + tx] = f2bf(tile[tx][r]);
}

// ---------------- Q' from q (angle-sum folding of rpe) + ktab (bh==0) -------
__global__ __launch_bounds__(256) void qprime_kernel(
    const short* __restrict__ qkv, short* __restrict__ qpr,
    short* __restrict__ ktab) {
  const int idx = blockIdx.x * 256 + threadIdx.x;  // 48*1024*32
  const int cc = idx & 31;
  const int row = idx >> 5;            // bh*1024 + i
  const int i = row & 1023, bh = row >> 10;
  const int b = bh / 12, h = bh % 12;
  const float invf = exp2f(-(float)cc * (13.287712379549449f / 32.0f));
  const float ang = (float)i * invf;
  float si, co;
  __sincosf(ang, &si, &co);
  if (bh == 0) {
    ktab[i * 64 + cc]      = f2bf(co);
    ktab[i * 64 + 32 + cc] = f2bf(si);
  }
  const short* q = qkv + (size_t)(b * 1024 + i) * 2304 + h * 64;
  const float qs = bf2f(q[cc]), qc = bf2f(q[32 + cc]);
  qpr[(size_t)row * 64 + cc]      = f2bf(qs * si + qc * co);
  qpr[(size_t)row * 64 + 32 + cc] = f2bf(qc * si - qs * co);
}

// ---------------- LayerNorm fp32 row(768) -> bf16 ----------------
__global__ __launch_bounds__(256) void ln_kernel(
    const float* __restrict__ x, const float* __restrict__ w,
    short* __restrict__ out) {
  const int row = blockIdx.x, tid = threadIdx.x;
  const float* xr = x + (size_t)row * 768;
  float v0 = xr[tid], v1 = xr[tid + 256], v2 = xr[tid + 512];
  float s = v0 + v1 + v2;
  #pragma unroll
  for (int o = 1; o < 64; o <<= 1) s += __shfl_xor(s, o);
  __shared__ float red[8];
  const int wv = tid >> 6;
  if ((tid & 63) == 0) red[wv] = s;
  __syncthreads();
  const float mean = (red[0] + red[1] + red[2] + red[3]) * (1.0f / 768.0f);
  v0 -= mean; v1 -= mean; v2 -= mean;
  float q = v0 * v0 + v1 * v1 + v2 * v2;
  #pragma unroll
  for (int o = 1; o < 64; o <<= 1) q += __shfl_xor(q, o);
  if ((tid & 63) == 0) red[4 + wv] = q;
  __syncthreads();
  const float var = (red[4] + red[5] + red[6] + red[7]) * (1.0f / 768.0f);
  const float inv = 1.0f / sqrtf(var + 1e-5f);
  out[(size_t)row * 768 + tid]       = f2bf(v0 * inv * w[tid]);
  out[(size_t)row * 768 + tid + 256] = f2bf(v1 * inv * w[tid + 256]);
  out[(size_t)row * 768 + tid + 512] = f2bf(v2 * inv * w[tid + 512]);
}

// ---------------- V transpose: qkv v-part -> vT[b,h,d,t] ----------------
__global__ __launch_bounds__(256) void vtrans_kernel(
    const short* __restrict__ qkv, short* __restrict__ vT) {
  __shared__ short tile[64][65];
  const int blk = blockIdx.x;
  const int bh = blk >> 4, t0 = (blk & 15) * 64;
  const int b = bh / 12, h = bh % 12;
  const int tx = threadIdx.x & 63, ty = threadIdx.x >> 6;
  const short* src = qkv + (size_t)(b * 1024 + t0) * 2304 + 1536 + h * 64;
  #pragma unroll
  for (int r = ty; r < 64; r += 4)
    tile[r][tx] = src[(size_t)r * 2304 + tx];
  __syncthreads();
  short* dst = vT + (size_t)bh * 64 * 1024 + t0;
  #pragma unroll
  for (int r = ty; r < 64; r += 4)
    dst[(size_t)r * 1024 + tx] = tile[tx][r];
}

// ---------------- GEMM: C[M,N] = A[M,K](bf16) x Bt[N,K](bf16) ----------------
// 2-phase double-buffered global_load_lds staging; ONE barrier per K-step.
// T1 XCD-aware bijective block swizzle: each XCD gets a contiguous x-fastest
// chunk of the grid -> A panels read once device-wide (grid size must be %8).
// EPI 0: bf16 store  1: f32 out=res+acc  2: bf16 gelu  3: f32 split-K partial
template <int EPI, int BM, int BN>
__global__ __launch_bounds__(256) void gemm_bt(
    const short* __restrict__ A, const short* __restrict__ Bt,
    const float* __restrict__ res, float* __restrict__ outF,
    short* __restrict__ outB, int M, int N, int K, int lda, int ldb) {
  __shared__ __align__(16) short As[2][BM * 32];
  __shared__ __align__(16) short Bs[2][BN * 32];
  constexpr int WM = BM / 2, WN = BN / 2;
  constexpr int MI = WM / 16, NJ = WN / 16;
  const int tid = threadIdx.x;
  const int w = tid >> 6, lane = tid & 63;
  // ---- XCD swizzle (dispatch order = x-fastest linear; XCD = lin % 8) ----
  const int gx = gridDim.x, gy = gridDim.y;
  const int nwg = gx * gy * gridDim.z;
  const int lin = blockIdx.x + gx * (blockIdx.y + gy * blockIdx.z);
  const int wg = (lin & 7) * (nwg >> 3) + (lin >> 3);
  const int bxi = wg % gx;
  const int tmp = wg / gx;
  const int byi = tmp % gy;
  const int bzi = tmp / gy;
  const int m0 = byi * BM, n0 = bxi * BN;
  const int wm = (w >> 1) * WM, wn = (w & 1) * WN;
  const int lr = lane >> 2;
  const int lc = (lane & 3) * 8;
  if constexpr (EPI == 3) {
    A += (size_t)bzi * K;
    Bt += (size_t)bzi * K;
    outF += (size_t)bzi * M * N;
  }
  f32x4 acc[MI][NJ];
  #pragma unroll
  for (int i = 0; i < MI; i++)
    #pragma unroll
    for (int j = 0; j < NJ; j++)
      #pragma unroll
      for (int r = 0; r < 4; r++) acc[i][j][r] = 0.0f;

  const int nt = K / 32;
  // prologue stage into buf 0
  #pragma unroll
  for (int p = 0; p < BM / 64; ++p)
    gload16(A + (size_t)(m0 + p * 64 + w * 16 + lr) * lda + lc,
            &As[0][p * 2048 + w * 512]);
  #pragma unroll
  for (int p = 0; p < BN / 64; ++p)
    gload16(Bt + (size_t)(n0 + p * 64 + w * 16 + lr) * ldb + lc,
            &Bs[0][p * 2048 + w * 512]);
  __syncthreads();

  for (int t = 0; t < nt; ++t) {
    const int cur = t & 1;
    if (t + 1 < nt) {
      const int kt = (t + 1) * 32;
      #pragma unroll
      for (int p = 0; p < BM / 64; ++p)
        gload16(A + (size_t)(m0 + p * 64 + w * 16 + lr) * lda + kt + lc,
                &As[cur ^ 1][p * 2048 + w * 512]);
      #pragma unroll
      for (int p = 0; p < BN / 64; ++p)
        gload16(Bt + (size_t)(n0 + p * 64 + w * 16 + lr) * ldb + kt + lc,
                &Bs[cur ^ 1][p * 2048 + w * 512]);
    }
    bf16x8 af[MI], bfr[NJ];
    #pragma unroll
    for (int i = 0; i < MI; i++)
      af[i] = *(const bf16x8*)&As[cur][(wm + i * 16 + (lane & 15)) * 32 + (lane >> 4) * 8];
    #pragma unroll
    for (int j = 0; j < NJ; j++)
      bfr[j] = *(const bf16x8*)&Bs[cur][(wn + j * 16 + (lane & 15)) * 32 + (lane >> 4) * 8];
    #pragma unroll
    for (int i = 0; i < MI; i++)
      #pragma unroll
      for (int j = 0; j < NJ; j++)
        acc[i][j] = __builtin_amdgcn_mfma_f32_16x16x32_bf16(af[i], bfr[j],
                                                            acc[i][j], 0, 0, 0);
    __syncthreads();
  }
  const int r0 = (lane >> 4) * 4, cl = lane & 15;
  #pragma unroll
  for (int i = 0; i < MI; i++) {
    #pragma unroll
    for (int j = 0; j < NJ; j++) {
      const int gm = m0 + wm + i * 16 + r0;
      const int gn = n0 + wn + j * 16 + cl;
      #pragma unroll
      for (int r = 0; r < 4; r++) {
        const size_t idx = (size_t)(gm + r) * N + gn;
        const float v = acc[i][j][r];
        if constexpr (EPI == 0) {
          outB[idx] = f2bf(v);
        } else if constexpr (EPI == 1) {
          outF[idx] = res[idx] + v;
        } else if constexpr (EPI == 2) {
          outB[idx] = f2bf(0.5f * v * (1.0f + erff(v * 0.70710678118f)));
        } else {
          outF[idx] = v;
        }
      }
    }
  }
}

// ---------------- split-K=2 reduce: out = res + sum_z Cp[z] ----------------
__global__ __launch_bounds__(256) void reduce_splitk(
    const float* __restrict__ Cp, const float* __restrict__ res,
    float* __restrict__ out) {
  const size_t i4 = ((size_t)blockIdx.x * 256 + threadIdx.x) * 4;
  float4 a = *(const float4*)(res + i4);
  #pragma unroll
  for (int z = 0; z < 2; ++z) {
    float4 p = *(const float4*)(Cp + (size_t)z * 3145728 + i4);
    a.x += p.x; a.y += p.y; a.z += p.z; a.w += p.w;
  }
  *(float4*)(out + i4) = a;
}

// ---------------- attention partials: cooperative LDS-staged j-window -------
// block = (bh, window c, sub). All 8 waves share the SAME 4-tile j-window
// [4c, 4c+3]; wave w owns it = 4c + sub*8 + w (idle if it>31; diag waves stop
// at jt=it). Kaug(K||ktab) and V staged in LDS, double-buffered, async split.
// Task index (R6-compatible): task = bh*144 + it + 30c - 2c^2.
__global__ __launch_bounds__(512) void attn_part8(
    const short* __restrict__ qkv, const short* __restrict__ vT,
    const short* __restrict__ qpr, const short* __restrict__ ktab,
    float* __restrict__ mpart, float* __restrict__ lpart,
    short* __restrict__ Ypart) {
  __shared__ __align__(16) short Ka[2][32 * 136];  // row: [k(64) | ktab(64) | pad8]
  __shared__ __align__(16) short Va[2][64 * 40];   // row d: [v(32) | pad8]
  const int bx = blockIdx.x;
  const int bh = bx / 20;
  const int r = bx % 20;
  int c, sub;
  if (r < 4)        { c = 0; sub = r; }
  else if (r < 8)   { c = 1; sub = r - 4; }
  else if (r < 11)  { c = 2; sub = r - 8; }
  else if (r < 14)  { c = 3; sub = r - 11; }
  else if (r < 16)  { c = 4; sub = r - 14; }
  else if (r < 18)  { c = 5; sub = r - 16; }
  else if (r == 18) { c = 6; sub = 0; }
  else              { c = 7; sub = 0; }
  const int tid = threadIdx.x;
  const int w = tid >> 6;
  const int lane = tid & 63;
  const int li = lane & 31, hi = lane >> 5;
  const int it = 4 * c + sub * 8 + w;
  const bool valid = (it <= 31);
  const int b = bh / 12, h = bh % 12;
  const int I0 = (valid ? it : 31) * 32;
  const int jt0 = 4 * c;
  const int jtmax = valid ? ((it < jt0 + 3) ? it : jt0 + 3) : (jt0 - 1);
  constexpr float SCALE2 = 0.125f * 1.44269504089f;  // 1/sqrt(64) * log2(e)

  const short* kbase = qkv + (size_t)(b * 1024) * 2304 + 768 + h * 64;
  const short* vbase = vT + (size_t)bh * 64 * 1024;

  // staging roles: Kaug = 32 rows x 256B = 512 x 16B chunks (1/thread);
  // V = 64 rows x 64B = 256 chunks (threads 0..255).
  const int krow = tid >> 4, kch = tid & 15;
  const short* ksrc = (kch < 8) ? (kbase + kch * 8) : (ktab + (kch - 8) * 8);
  const size_t kstr = (kch < 8) ? 2304 : 64;
  const int vrow = tid >> 2, vch = tid & 3;

  int4 kreg, vreg;
  {
    const int J0 = jt0 * 32;
    kreg = *(const int4*)(ksrc + (size_t)(J0 + krow) * kstr);
    if (tid < 256)
      vreg = *(const int4*)(vbase + (size_t)vrow * 1024 + J0 + vch * 8);
  }

  // Qaug fragments: [q(64) | Q'(64)] (clamped row for idle waves)
  const short* qrow = qkv + (size_t)(b * 1024 + I0 + li) * 2304 + h * 64;
  const short* qprow = qpr + ((size_t)bh * 1024 + I0 + li) * 64;
  bf16x8 qf[8];
  #pragma unroll
  for (int s = 0; s < 4; s++) {
    qf[s]     = *(const bf16x8*)(qrow + s * 16 + hi * 8);
    qf[4 + s] = *(const bf16x8*)(qprow + s * 16 + hi * 8);
  }

  *(int4*)&Ka[0][krow * 136 + kch * 8] = kreg;
  if (tid < 256) *(int4*)&Va[0][vrow * 40 + vch * 8] = vreg;
  __syncthreads();

  float m_run = -1e30f, l_run = 0.0f;
  f32x16 ya0, ya1;
  #pragma unroll
  for (int q = 0; q < 16; q++) { ya0[q] = 0.0f; ya1[q] = 0.0f; }

  for (int t = 0; t < 4; ++t) {
    const int cur = t & 1;
    // async-stage split: issue next tile's global loads before compute
    if (t < 3) {
      const int J0n = (jt0 + t + 1) * 32;
      kreg = *(const int4*)(ksrc + (size_t)(J0n + krow) * kstr);
      if (tid < 256)
        vreg = *(const int4*)(vbase + (size_t)vrow * 1024 + J0n + vch * 8);
    }
    const int jt = jt0 + t;
    if (jt <= jtmax) {
      // fragments from LDS
      bf16x8 kf[8];
      #pragma unroll
      for (int s = 0; s < 8; s++)
        kf[s] = *(const bf16x8*)&Ka[cur][li * 136 + s * 16 + hi * 8];
      bf16x8 vc[4];
      #pragma unroll
      for (int s = 0; s < 2; s++) {
        vc[s * 2]     = *(const bf16x8*)&Va[cur][li * 40 + s * 16 + hi * 8];
        vc[s * 2 + 1] = *(const bf16x8*)&Va[cur][(32 + li) * 40 + s * 16 + hi * 8];
      }
      // --- S^T = Kaug . Qaug^T, two independent chains ---
      f32x16 sa0, sa1;
      #pragma unroll
      for (int q = 0; q < 16; q++) { sa0[q] = 0.0f; sa1[q] = 0.0f; }
      __builtin_amdgcn_s_setprio(1);
      #pragma unroll
      for (int s = 0; s < 4; s++) {
        sa0 = __builtin_amdgcn_mfma_f32_32x32x16_bf16(kf[2 * s],     qf[2 * s],     sa0, 0, 0, 0);
        sa1 = __builtin_amdgcn_mfma_f32_32x32x16_bf16(kf[2 * s + 1], qf[2 * s + 1], sa1, 0, 0, 0);
      }
      __builtin_amdgcn_s_setprio(0);
      // --- scale (log2 domain), mask only diagonal tile, online softmax ---
      float sv[16];
      float mx = -1e30f;
      if (jt == it) {
        #pragma unroll
        for (int q = 0; q < 16; q++) {
          const int j = (q & 3) + 8 * (q >> 2) + 4 * hi;
          float v = (sa0[q] + sa1[q]) * SCALE2;
          v = (j <= li) ? v : -1e30f;
          sv[q] = v;
          mx = fmaxf(mx, v);
        }
      } else {
        #pragma unroll
        for (int q = 0; q < 16; q++) {
          const float v = (sa0[q] + sa1[q]) * SCALE2;
          sv[q] = v;
          mx = fmaxf(mx, v);
        }
      }
      mx = fmaxf(mx, __shfl_xor(mx, 32));
      float mref = m_run;
      float alpha = 1.0f;
      const bool resc = !__all(mx <= m_run + 11.5f);  // defer-max (T13)
      if (resc) {
        mref = fmaxf(m_run, mx);
        alpha = exp2f(m_run - mref);
        m_run = mref;
      }
      float psum = 0.0f;
      unsigned pw[8];
      #pragma unroll
      for (int q = 0; q < 8; q++) {
        const float p0 = exp2f(sv[2 * q] - mref);
        const float p1 = exp2f(sv[2 * q + 1] - mref);
        psum += p0 + p1;
        pw[q] = cvt_pk_bf16(p0, p1);
      }
      psum += __shfl_xor(psum, 32);
      l_run = l_run * alpha + psum;
      if (resc) {
        #pragma unroll
        for (int q = 0; q < 16; q++) {
          const int row = (q & 3) + 8 * (q >> 2) + 4 * hi;
          const float a = __shfl(alpha, row);
          ya0[q] *= a;
          ya1[q] *= a;
        }
      }
      // --- PV: redistribute P via permlane32_swap, then MFMA ---
      #pragma unroll
      for (int s = 0; s < 2; s++) {
        unsigned a0 = pw[4 * s],     b0 = pw[4 * s + 2];
        unsigned a1 = pw[4 * s + 1], b1 = pw[4 * s + 3];
        asm volatile("v_permlane32_swap_b32 %0, %1" : "+v"(a0), "+v"(b0));
        asm volatile("v_permlane32_swap_b32 %0, %1" : "+v"(a1), "+v"(b1));
        u32x4 t4;
        t4[0] = a0; t4[1] = a1; t4[2] = b0; t4[3] = b1;
        const bf16x8 pf = __builtin_bit_cast(bf16x8, t4);
        __builtin_amdgcn_s_setprio(1);
        ya0 = __builtin_amdgcn_mfma_f32_32x32x16_bf16(pf, vc[s * 2],     ya0, 0, 0, 0);
        ya1 = __builtin_amdgcn_mfma_f32_32x32x16_bf16(pf, vc[s * 2 + 1], ya1, 0, 0, 0);
        __builtin_amdgcn_s_setprio(0);
      }
    }
    // write next buffer (other buffer than the one being read this iter)
    if (t < 3) {
      *(int4*)&Ka[cur ^ 1][krow * 136 + kch * 8] = kreg;
      if (tid < 256) *(int4*)&Va[cur ^ 1][vrow * 40 + vch * 8] = vreg;
    }
    __syncthreads();
  }
  if (!valid) return;
  // --- write partials: m, l per row; unnormalized Y (bf16) ---
  const int task = bh * 144 + it + 30 * c - 2 * c * c;
  if (hi == 0) {
    mpart[(size_t)task * 32 + li] = m_run;
    lpart[(size_t)task * 32 + li] = l_run;
  }
  short* yb = Ypart + (size_t)task * 2048;
  #pragma unroll
  for (int q = 0; q < 16; q++) {
    const int row = (q & 3) + 8 * (q >> 2) + 4 * hi;
    yb[row * 64 + li]      = f2bf(ya0[q]);
    yb[row * 64 + 32 + li] = f2bf(ya1[q]);
  }
}

// ---------------- attention combine: merge <=8 chunks (c-major layout) ------
__global__ __launch_bounds__(256) void attn_combine(
    const float* __restrict__ mpart, const float* __restrict__ lpart,
    const short* __restrict__ Ypart, short* __restrict__ yout) {
  const int blk = blockIdx.x;  // bh*32 + it
  const int it = blk & 31, bh = blk >> 5;
  const int b = bh / 12, h = bh % 12;
  const int g = it >> 2;
  const int nc = g + 1;
  const int row = threadIdx.x >> 3;
  const int c0 = (threadIdx.x & 7) * 8;
  // chunk cI lives at task index bh*144 + it + 30*cI - 2*cI*cI
  float mv[8], lv[8], wgt[8];
  float m = -1e30f;
  #pragma unroll
  for (int cI = 0; cI < 8; ++cI) {
    const int idx = bh * 144 + it + 30 * cI - 2 * cI * cI;
    mv[cI] = (cI < nc) ? mpart[(size_t)idx * 32 + row] : -1e30f;
    lv[cI] = (cI < nc) ? lpart[(size_t)idx * 32 + row] : 0.0f;
    m = fmaxf(m, mv[cI]);
  }
  float L = 0.0f;
  #pragma unroll
  for (int cI = 0; cI < 8; ++cI) {
    wgt[cI] = exp2f(mv[cI] - m);
    L += lv[cI] * wgt[cI];
  }
  const float inv = 1.0f / L;
  float y[8];
  #pragma unroll
  for (int r = 0; r < 8; r++) y[r] = 0.0f;
  #pragma unroll
  for (int cI = 0; cI < 8; ++cI) {
    if (cI < nc) {
      const int idx = bh * 144 + it + 30 * cI - 2 * cI * cI;
      bf16x8 v = *(const bf16x8*)(Ypart + ((size_t)idx * 32 + row) * 64 + c0);
      #pragma unroll
      for (int r = 0; r < 8; r++) y[r] += bf2f(v[r]) * wgt[cI];
    }
  }
  short* dst = yout + (size_t)(b * 1024 + it * 32 + row) * 768 + h * 64 + c0;
  #pragma unroll
  for (int r = 0; r < 8; r++) dst[r] = f2bf(y[r] * inv);
}

// ---------------- launch ----------------
extern "C" void kernel_launch(void* const* d_in, const int* in_sizes, int n_in,
                              void* d_out, int out_size, void* d_ws, size_t ws_size,
                              hipStream_t stream) {
  const float* x       = (const float*)d_in[0];
  const float* ln1_w   = (const float*)d_in[1];
  const float* w_attn  = (const float*)d_in[2];
  // d_in[3] = w_pos (dead code in reference)
  const float* w_cproj = (const float*)d_in[4];
  const float* ln2_w   = (const float*)d_in[5];
  const float* w_fc    = (const float*)d_in[6];
  const float* w_mproj = (const float*)d_in[7];
  float* out = (float*)d_out;
  char* ws = (char*)d_ws;

  short* wT_attn  = (short*)(ws + 0);          // [2304][768]
  short* wT_cproj = (short*)(ws + 3538944);    // [768][768]
  short* wT_fc    = (short*)(ws + 4718592);    // [3072][768]
  short* wT_mproj = (short*)(ws + 9437184);    // [768][3072]
  short* ktab     = (short*)(ws + 14155776);   // [1024][64] bf16 (128KB)
  short* h_bf     = (short*)(ws + 14417920);   // [4096][768]; reused as qpr
  short* qpr      = (short*)(ws + 14417920);   // [48*1024][64] (h_bf dead then)
  short* qkv_bf   = (short*)(ws + 20709376);   // [4096][2304]
  short* vT       = (short*)(ws + 39583744);   // [48][64][1024]
  short* y_att    = (short*)(ws + 45875200);   // [4096][768]
  short* h2_bf    = (short*)(ws + 52166656);   // [4096][768]
  short* hfc_bf   = (short*)(ws + 58458112);   // [4096][3072]
  // attention partials alias the (not-yet-live) MLP buffers:
  float* mpart = (float*)(ws + 52166656);      // [6912][32] f32
  float* lpart = (float*)(ws + 53051392);      // [6912][32] f32
  short* Ypart = (short*)(ws + 53936128);      // [6912][32][64] bf16 (28.3MB)
  // mproj split-K=2 partials alias dead qkv_bf+vT: 2 x [4096][768] f32
  float* Cpart = (float*)(ws + 20709376);      // 25165824 B exactly

  // weight prep
  wtrans_all<<<6912, 256, 0, stream>>>(w_attn, w_cproj, w_fc, w_mproj,
                                       wT_attn, wT_cproj, wT_fc, wT_mproj);

  // attention branch
  ln_kernel<<<4096, 256, 0, stream>>>(x, ln1_w, h_bf);
  gemm_bt<0, 128, 128><<<dim3(18, 32), 256, 0, stream>>>(
      h_bf, wT_attn, nullptr, nullptr, qkv_bf, 4096, 2304, 768, 768, 768);
  qprime_kernel<<<6144, 256, 0, stream>>>(qkv_bf, qpr, ktab);
  vtrans_kernel<<<768, 256, 0, stream>>>(qkv_bf, vT);
  attn_part8<<<960, 512, 0, stream>>>(qkv_bf, vT, qpr, ktab, mpart, lpart, Ypart);
  attn_combine<<<1536, 256, 0, stream>>>(mpart, lpart, Ypart, y_att);
  gemm_bt<1, 64, 64><<<dim3(12, 64), 256, 0, stream>>>(
      y_att, wT_cproj, x, out, nullptr, 4096, 768, 768, 768, 768);
  // MLP branch
  ln_kernel<<<4096, 256, 0, stream>>>(out, ln2_w, h2_bf);
  gemm_bt<2, 128, 128><<<dim3(24, 32), 256, 0, stream>>>(
      h2_bf, wT_fc, nullptr, nullptr, hfc_bf, 4096, 3072, 768, 768, 768);
  // mproj: split-K=2 (qkv_bf/vT are dead by now; Cpart aliases them)
  gemm_bt<3, 128, 64><<<dim3(12, 32, 2), 256, 0, stream>>>(
      hfc_bf, wT_mproj, nullptr, Cpart, nullptr, 4096, 768, 1536, 3072, 3072);
  reduce_splitk<<<3072, 256, 0, stream>>>(Cpart, out, out);
}